// Round 8
// baseline (190.848 us; speedup 1.0000x reference)
//
#include <hip/hip_runtime.h>
#include <hip/hip_bf16.h>
#include <math.h>

typedef __attribute__((ext_vector_type(8))) __bf16 bf16x8;
typedef __attribute__((ext_vector_type(4))) __bf16 bf16x4;
typedef __attribute__((ext_vector_type(4))) float f32x4;

#define DEVINL static __device__ __forceinline__

static constexpr int Tlen = 1024;
static constexpr int HD = 32;

DEVINL void gload_lds16(const void* g, void* l) {
  __builtin_amdgcn_global_load_lds(
      (const __attribute__((address_space(1))) void*)g,
      (__attribute__((address_space(3))) void*)l, 16, 0, 0);
}

DEVINL unsigned short bfbits(float x) {
  __bf16 b = (__bf16)x;
  return __builtin_bit_cast(unsigned short, b);
}

// ---------- small staging kernels ----------

__global__ void k_cvt_bf16(const float* __restrict__ in, __bf16* __restrict__ out, int n) {
  int i = (blockIdx.x * blockDim.x + threadIdx.x) * 8;
  if (i >= n) return;
  const float4* p = (const float4*)(in + i);
  float4 a = p[0], b = p[1];
  bf16x8 v;
  v[0] = (__bf16)a.x; v[1] = (__bf16)a.y; v[2] = (__bf16)a.z; v[3] = (__bf16)a.w;
  v[4] = (__bf16)b.x; v[5] = (__bf16)b.y; v[6] = (__bf16)b.z; v[7] = (__bf16)b.w;
  *(bf16x8*)(out + i) = v;
}

// w[K][N] fp32 -> wt[N][K] bf16. 64x64 tile, float4 loads, bf16x4 stores.
__global__ void k_transpose_bf16(const float* __restrict__ w, __bf16* __restrict__ wt,
                                 int K, int N) {
  __shared__ float tile[64][65];
  const int n0 = blockIdx.x * 64;
  const int k0 = blockIdx.y * 64;
  const int tx = threadIdx.x & 15;
  const int ty = threadIdx.x >> 4;
#pragma unroll
  for (int i = 0; i < 4; ++i) {
    float4 v = *(const float4*)&w[(size_t)(k0 + ty + i * 16) * N + n0 + tx * 4];
    tile[ty + i * 16][tx * 4 + 0] = v.x;
    tile[ty + i * 16][tx * 4 + 1] = v.y;
    tile[ty + i * 16][tx * 4 + 2] = v.z;
    tile[ty + i * 16][tx * 4 + 3] = v.w;
  }
  __syncthreads();
#pragma unroll
  for (int i = 0; i < 4; ++i) {
    int n = ty + i * 16;
    bf16x4 s;
#pragma unroll
    for (int j = 0; j < 4; ++j) s[j] = (__bf16)tile[tx * 4 + j][n];
    *(bf16x4*)&wt[(size_t)(n0 + n) * K + k0 + tx * 4] = s;
  }
}

__global__ void k_sincos(const float* __restrict__ pos, float* __restrict__ cosT,
                         float* __restrict__ sinT) {
  int idx = blockIdx.x * blockDim.x + threadIdx.x;  // T*32
  int t = idx >> 5, d = idx & 31;
  float invf = powf(10000.0f, -(float)d * (1.0f / 32.0f));
  float ang = pos[t] * invf;
  cosT[idx] = cosf(ang);
  sinT[idx] = sinf(ang);
}

// ---------- 256x256 GEMM, 2 merged phases per K-tile (4 barriers vs R4's 8) ----
// Experiment: isolate barrier-count cost. Same dbuf + counted-vmcnt + swizzles
// as R4's 8-phase (109.5us). Phase AB: reads A_mh0,B_nh0,B_nh1 -> 32 MFMA
// (m0-3 x n0-3). Phase CD: reads A_mh1 -> 32 MFMA (m4-7), B held in regs.
// vmcnt derivation (steady state, per-wave outstanding gloads):
//  AB(kt) end: pool = AB(kt-1):2[kt A1] + CD(kt-1):6[kt+1 A0B0B1] + AB(kt):2
//            = 10 -> vmcnt(8) drains kt's A1 (read by CD(kt)).
//  CD(kt) end: pool = CD(kt-1):6 + AB(kt):2 + CD(kt):6 = 14 -> vmcnt(8)
//            drains kt+1's A0B0B1 (read by AB(kt+1)).
// MODE 0: fp32 store. MODE 1: RoPE epilogue -> Q/K [B,H,T,32], V^T [B,H,32,T].
template <int MODE>
__launch_bounds__(512, 2)
__global__ void k_gemm8(const __bf16* __restrict__ A, const __bf16* __restrict__ Bt,
                        int M, int N, int K, float* __restrict__ Cout,
                        __bf16* __restrict__ Qo, __bf16* __restrict__ Ko,
                        __bf16* __restrict__ Vto, const float* __restrict__ cosT,
                        const float* __restrict__ sinT) {
  __shared__ alignas(16) __bf16 As[2][256 * 64];
  __shared__ alignas(16) __bf16 Bs[2][256 * 64];

  const int tid = threadIdx.x;
  const int lane = tid & 63;
  const int wave = tid >> 6;            // 0..7
  const int wr = wave >> 2, wc = wave & 3;
  const int l15 = lane & 15;
  const int g = lane >> 4;              // 0..3

  const int nwg = gridDim.x * gridDim.y;
  const int bid = blockIdx.y * gridDim.x + blockIdx.x;
  const int cpx = nwg >> 3;
  const int tswz = (bid & 7) * cpx + (bid >> 3);
  const int bx = tswz % gridDim.x, by = tswz / gridDim.x;
  const int m0 = by * 256, n0 = bx * 256;

  f32x4 acc[8][4] = {};

  const int srcChunkElem = ((lane & 7) ^ (lane >> 3)) * 8;
  const int laneRow = lane >> 3;        // 0..7
  const int NT = K >> 6;

  auto stageA = [&](int buf, int kt, int mh) {
    const int k0 = kt << 6;
#pragma unroll
    for (int i = 0; i < 2; ++i) {
      int gi = i * 8 + wave;                                // 0..15
      int rowstart = ((gi >> 3) << 7) + (mh << 6) + ((gi & 7) << 3);
      gload_lds16(A + (size_t)(m0 + rowstart + laneRow) * K + k0 + srcChunkElem,
                  &As[buf][rowstart * 64]);
    }
  };
  auto stageB = [&](int buf, int kt, int nh) {
    const int k0 = kt << 6;
#pragma unroll
    for (int i = 0; i < 2; ++i) {
      int gi = i * 8 + wave;
      int rowstart = ((gi >> 2) << 6) + (nh << 5) + ((gi & 3) << 3);
      gload_lds16(Bt + (size_t)(n0 + rowstart + laneRow) * K + k0 + srcChunkElem,
                  &Bs[buf][rowstart * 64]);
    }
  };

  // prologue: tile0 all 4 half-tiles (8), tile1 A0+B0+B1 (6)
  stageA(0, 0, 0); stageB(0, 0, 0); stageB(0, 0, 1); stageA(0, 0, 1);
  if (NT > 1) {
    stageA(1, 1, 0); stageB(1, 1, 0); stageB(1, 1, 1);
    asm volatile("s_waitcnt vmcnt(6)" ::: "memory");  // tile0 fully resident
  } else {
    asm volatile("s_waitcnt vmcnt(0)" ::: "memory");
  }
  __builtin_amdgcn_s_barrier();
  __builtin_amdgcn_sched_barrier(0);

  bf16x8 af[4][2], af2[4][2], bf0[2][2], bf1[2][2];

  for (int kt = 0; kt < NT; ++kt) {
    const int cur = kt & 1;
    const char* ab = (const char*)&As[cur][0];
    const char* bb = (const char*)&Bs[cur][0];

    // ---- phase AB: 16 ds_reads (A_mh0 + all B), 32 MFMA (m0..3, n0..3)
#pragma unroll
    for (int m = 0; m < 4; ++m)
#pragma unroll
      for (int hh = 0; hh < 2; ++hh) {
        int ar = wr * 128 + m * 16 + l15;
        int chunk = (4 * hh + g) ^ (lane & 7);
        af[m][hh] = *(const bf16x8*)(ab + ar * 128 + chunk * 16);
      }
#pragma unroll
    for (int n = 0; n < 2; ++n)
#pragma unroll
      for (int hh = 0; hh < 2; ++hh) {
        int br = wc * 64 + n * 16 + l15;
        int chunk = (4 * hh + g) ^ (lane & 7);
        bf0[n][hh] = *(const bf16x8*)(bb + br * 128 + chunk * 16);
      }
#pragma unroll
    for (int n = 0; n < 2; ++n)
#pragma unroll
      for (int hh = 0; hh < 2; ++hh) {
        int br = wc * 64 + 32 + n * 16 + l15;
        int chunk = (4 * hh + g) ^ (lane & 7);
        bf1[n][hh] = *(const bf16x8*)(bb + br * 128 + chunk * 16);
      }
    if (kt + 1 < NT) stageA(cur ^ 1, kt + 1, 1);   // kt+1's A1 (2 gloads)
    asm volatile("s_waitcnt lgkmcnt(8)" ::: "memory");  // partial drain under barrier
    __builtin_amdgcn_s_barrier();
    asm volatile("s_waitcnt lgkmcnt(0)" ::: "memory");
    __builtin_amdgcn_sched_barrier(0);
    __builtin_amdgcn_s_setprio(1);
#pragma unroll
    for (int hh = 0; hh < 2; ++hh)
#pragma unroll
      for (int m = 0; m < 4; ++m) {
#pragma unroll
        for (int n = 0; n < 2; ++n)
          acc[m][n] = __builtin_amdgcn_mfma_f32_16x16x32_bf16(af[m][hh], bf0[n][hh], acc[m][n], 0, 0, 0);
#pragma unroll
        for (int n = 0; n < 2; ++n)
          acc[m][n + 2] = __builtin_amdgcn_mfma_f32_16x16x32_bf16(af[m][hh], bf1[n][hh], acc[m][n + 2], 0, 0, 0);
      }
    __builtin_amdgcn_s_setprio(0);
    __builtin_amdgcn_sched_barrier(0);
    if (kt + 1 < NT) {
      asm volatile("s_waitcnt vmcnt(8)" ::: "memory");   // kt's A1 resident for CD
    } else {
      asm volatile("s_waitcnt vmcnt(0)" ::: "memory");
    }
    __builtin_amdgcn_s_barrier();
    __builtin_amdgcn_sched_barrier(0);

    // ---- phase CD: 8 ds_reads (A_mh1), 32 MFMA (m4..7, n0..3); B in regs
#pragma unroll
    for (int m = 0; m < 4; ++m)
#pragma unroll
      for (int hh = 0; hh < 2; ++hh) {
        int ar = wr * 128 + 64 + m * 16 + l15;
        int chunk = (4 * hh + g) ^ (lane & 7);
        af2[m][hh] = *(const bf16x8*)(ab + ar * 128 + chunk * 16);
      }
    if (kt + 2 < NT) {  // kt+2's A0,B0,B1 (6 gloads) into buf cur
      stageA(cur, kt + 2, 0); stageB(cur, kt + 2, 0); stageB(cur, kt + 2, 1);
    }
    __builtin_amdgcn_s_barrier();
    asm volatile("s_waitcnt lgkmcnt(0)" ::: "memory");
    __builtin_amdgcn_sched_barrier(0);
    __builtin_amdgcn_s_setprio(1);
#pragma unroll
    for (int hh = 0; hh < 2; ++hh)
#pragma unroll
      for (int m = 0; m < 4; ++m) {
#pragma unroll
        for (int n = 0; n < 2; ++n)
          acc[m + 4][n] = __builtin_amdgcn_mfma_f32_16x16x32_bf16(af2[m][hh], bf0[n][hh], acc[m + 4][n], 0, 0, 0);
#pragma unroll
        for (int n = 0; n < 2; ++n)
          acc[m + 4][n + 2] = __builtin_amdgcn_mfma_f32_16x16x32_bf16(af2[m][hh], bf1[n][hh], acc[m + 4][n + 2], 0, 0, 0);
      }
    __builtin_amdgcn_s_setprio(0);
    __builtin_amdgcn_sched_barrier(0);
    if (kt + 2 < NT) {
      asm volatile("s_waitcnt vmcnt(8)" ::: "memory");   // kt+1's A0B0B1 resident
    } else if (kt + 1 < NT) {
      asm volatile("s_waitcnt vmcnt(2)" ::: "memory");
    }
    if (kt + 1 < NT) {
      __builtin_amdgcn_s_barrier();
      __builtin_amdgcn_sched_barrier(0);
    }
  }

  // epilogue
#pragma unroll
  for (int m = 0; m < 8; ++m) {
    int row_l = wr * 128 + m * 16 + (g << 2);
#pragma unroll
    for (int n = 0; n < 4; ++n) {
      int col = n0 + wc * 64 + n * 16 + l15;
#pragma unroll
      for (int r = 0; r < 4; ++r) {
        int row = m0 + row_l + r;
        float v = acc[m][n][r];
        if (MODE == 0) {
          Cout[(size_t)row * N + col] = v;
        } else {
          int b = row >> 10, t = row & 1023;
          int sec = col >> 11;           // 0=q,1=k,2=v
          int c2 = col & 2047;
          int h = c2 >> 5, d = c2 & 31;
          float partner = __shfl_xor(v, 1);
          if (sec < 2) {
            float rot = (d & 1) ? partner : -partner;
            float cs = cosT[t * 32 + d], sn = sinT[t * 32 + d];
            float o = v * cs + rot * sn;
            if (sec == 0) o *= 0.17677669529663687f;  // fold 1/sqrt(hd) into Q
            __bf16* dst = sec ? Ko : Qo;
            dst[((size_t)((b << 6) | h) * Tlen + t) * HD + d] = (__bf16)o;
          } else {
            Vto[((size_t)((b << 6) | h) * HD + d) * Tlen + t] = (__bf16)v;
          }
        }
      }
    }
  }
}

// ---------- 2-phase 128x128 GEMM (for the projection; R4 config) ----------
template <int BM, int BN, int WM, int WN>
__launch_bounds__(WM * WN * 64)
__global__ void k_gemm(const __bf16* __restrict__ A, const __bf16* __restrict__ Bt,
                       int M, int N, int K, float* __restrict__ Cout) {
  constexpr int T = WM * WN * 64;
  constexpr int M_rep = BM / (WM * 16);
  constexpr int N_rep = BN / (WN * 16);
  constexpr int nA = (BM * 128) / (T * 16);
  constexpr int nB = (BN * 128) / (T * 16);
  constexpr int ROWS_PER_ISSUE = T / 8;

  __shared__ alignas(16) __bf16 As[2][BM * 64];
  __shared__ alignas(16) __bf16 Bs[2][BN * 64];

  const int tid = threadIdx.x;
  const int lane = tid & 63;
  const int wave = tid >> 6;
  const int wr = wave / WN, wc = wave % WN;
  const int l15 = lane & 15;

  const int nwg = gridDim.x * gridDim.y;
  const int bid = blockIdx.y * gridDim.x + blockIdx.x;
  const int cpx = nwg >> 3;
  const int tswz = (bid & 7) * cpx + (bid >> 3);
  const int bx = tswz % gridDim.x, by = tswz / gridDim.x;
  const int m0 = by * BM, n0 = bx * BN;

  f32x4 acc[M_rep][N_rep] = {};

  const int srcChunkElem = ((lane & 7) ^ (lane >> 3)) * 8;
  const int rowInWave = wave * 8 + (lane >> 3);

  const int NT = K >> 6;

  auto stage = [&](int buf, int kt) {
    const int k0 = kt << 6;
#pragma unroll
    for (int i = 0; i < nA; ++i) {
      int row = i * ROWS_PER_ISSUE + rowInWave;
      gload_lds16(A + (size_t)(m0 + row) * K + k0 + srcChunkElem,
                  &As[buf][(i * T + wave * 64) * 8]);
    }
#pragma unroll
    for (int i = 0; i < nB; ++i) {
      int row = i * ROWS_PER_ISSUE + rowInWave;
      gload_lds16(Bt + (size_t)(n0 + row) * K + k0 + srcChunkElem,
                  &Bs[buf][(i * T + wave * 64) * 8]);
    }
  };

  stage(0, 0);

  for (int kt = 0; kt < NT; ++kt) {
    const int cur = kt & 1;
    if (kt + 1 < NT) {
      stage(cur ^ 1, kt + 1);
      asm volatile("s_waitcnt vmcnt(8)" ::: "memory");
    } else {
      asm volatile("s_waitcnt vmcnt(0)" ::: "memory");
    }
    __builtin_amdgcn_s_barrier();
    __builtin_amdgcn_sched_barrier(0);

    const char* ab = (const char*)&As[cur][0];
    const char* bb = (const char*)&Bs[cur][0];
#pragma unroll
    for (int hh = 0; hh < 2; ++hh) {
      bf16x8 af[M_rep], bfv[N_rep];
#pragma unroll
      for (int m = 0; m < M_rep; ++m) {
        int ar = wr * (M_rep * 16) + m * 16 + l15;
        int chunk = ((4 * hh + (lane >> 4)) ^ (lane & 7));
        af[m] = *(const bf16x8*)(ab + ar * 128 + chunk * 16);
      }
#pragma unroll
      for (int n = 0; n < N_rep; ++n) {
        int br = wc * (N_rep * 16) + n * 16 + l15;
        int chunk = ((4 * hh + (lane >> 4)) ^ (lane & 7));
        bfv[n] = *(const bf16x8*)(bb + br * 128 + chunk * 16);
      }
      __builtin_amdgcn_s_setprio(1);
#pragma unroll
      for (int m = 0; m < M_rep; ++m)
#pragma unroll
        for (int n = 0; n < N_rep; ++n)
          acc[m][n] = __builtin_amdgcn_mfma_f32_16x16x32_bf16(af[m], bfv[n], acc[m][n], 0, 0, 0);
      __builtin_amdgcn_s_setprio(0);
    }
    __builtin_amdgcn_sched_barrier(0);
    __builtin_amdgcn_s_barrier();
  }

#pragma unroll
  for (int m = 0; m < M_rep; ++m) {
    int row_l = wr * (M_rep * 16) + m * 16 + ((lane >> 4) << 2);
#pragma unroll
    for (int n = 0; n < N_rep; ++n) {
      int col = n0 + wc * (N_rep * 16) + n * 16 + l15;
#pragma unroll
      for (int r = 0; r < 4; ++r) {
        int row = m0 + row_l + r;
        Cout[(size_t)row * N + col] = acc[m][n][r];
      }
    }
  }
}

// ---------- flash attention: swapped QK^T, KVBLK=64, static softmax ----------
__launch_bounds__(256)
__global__ void k_attn(const __bf16* __restrict__ Q, const __bf16* __restrict__ Kmat,
                       const __bf16* __restrict__ Vt, __bf16* __restrict__ att) {
  __shared__ alignas(16) __bf16 P[4][32 * 72];
  const int tid = threadIdx.x;
  const int lane = tid & 63;
  const int w = tid >> 6;

  const int orig = blockIdx.y * gridDim.x + blockIdx.x;  // [0,1024)
  const int idx = orig >> 3;                             // [0,128)
  const int bh = (orig & 7) * 16 + (idx >> 3);           // 16 heads per XCD
  const int j = idx & 7;                                 // [0,8)

  const int qt = (w == 0) ? 2 * j : (w == 1) ? 2 * j + 1 : (w == 2) ? 30 - 2 * j : 31 - 2 * j;
  const int q0 = qt * 32;

  const __bf16* Qb = Q + (size_t)bh * Tlen * HD;
  const __bf16* Kb = Kmat + (size_t)bh * Tlen * HD;
  const __bf16* Vb = Vt + (size_t)bh * HD * Tlen;
  __bf16* Pw = &P[w][0];

  const int l15 = lane & 15;
  const int g = lane >> 4;
  const int lk8 = g * 8;

  bf16x8 qf[2];
#pragma unroll
  for (int m = 0; m < 2; ++m)
    qf[m] = *(const bf16x8*)(Qb + (size_t)(q0 + m * 16 + l15) * HD + lk8);

  f32x4 o[2][2] = {};
  float lsum[2] = {0.f, 0.f};

  const int nfull = q0 >> 6;

  for (int kt = 0; kt <= nfull; ++kt) {
    const int k0 = kt * 64;
    bf16x8 kf[4];
#pragma unroll
    for (int n = 0; n < 4; ++n)
      kf[n] = *(const bf16x8*)(Kb + (size_t)(k0 + n * 16 + l15) * HD + lk8);

    f32x4 st[4][2] = {};
#pragma unroll
    for (int n = 0; n < 4; ++n)
#pragma unroll
      for (int m = 0; m < 2; ++m)
        st[n][m] = __builtin_amdgcn_mfma_f32_16x16x32_bf16(kf[n], qf[m], st[n][m], 0, 0, 0);

    bf16x8 vf[2][2];
#pragma unroll
    for (int nn = 0; nn < 2; ++nn)
#pragma unroll
      for (int c = 0; c < 2; ++c)
        vf[nn][c] = *(const bf16x8*)(Vb + (size_t)(nn * 16 + l15) * Tlen + k0 + c * 32 + lk8);

    if (kt == nfull) {
#pragma unroll
      for (int n = 0; n < 4; ++n)
#pragma unroll
        for (int m = 0; m < 2; ++m)
#pragma unroll
          for (int r = 0; r < 4; ++r) {
            int kk = k0 + n * 16 + 4 * g + r;
            int qq = q0 + m * 16 + l15;
            if (kk > qq) st[n][m][r] = -1e30f;
          }
    }

#pragma unroll
    for (int m = 0; m < 2; ++m) {
      float p[16];
      float ps = 0.f;
#pragma unroll
      for (int n = 0; n < 4; ++n)
#pragma unroll
        for (int r = 0; r < 4; ++r) {
          float pv = __expf(st[n][m][r]);
          p[n * 4 + r] = pv;
          ps += pv;
        }
      ps += __shfl_xor(ps, 16);
      ps += __shfl_xor(ps, 32);
      lsum[m] += ps;

#pragma unroll
      for (int n = 0; n < 4; ++n) {
        unsigned int u0 = ((unsigned int)bfbits(p[n * 4 + 1]) << 16) | bfbits(p[n * 4 + 0]);
        unsigned int u1 = ((unsigned int)bfbits(p[n * 4 + 3]) << 16) | bfbits(p[n * 4 + 2]);
        int base = (m * 16 + l15) * 72 + n * 16 + 4 * g;
        *(unsigned int*)&Pw[base] = u0;
        *(unsigned int*)&Pw[base + 2] = u1;
      }
    }

    bf16x8 pa[2][2];
#pragma unroll
    for (int m = 0; m < 2; ++m)
#pragma unroll
      for (int c = 0; c < 2; ++c)
        pa[m][c] = *(const bf16x8*)&Pw[(m * 16 + l15) * 72 + c * 32 + lk8];

#pragma unroll
    for (int m = 0; m < 2; ++m)
#pragma unroll
      for (int nn = 0; nn < 2; ++nn)
#pragma unroll
        for (int c = 0; c < 2; ++c)
          o[m][nn] = __builtin_amdgcn_mfma_f32_16x16x32_bf16(pa[m][c], vf[nn][c], o[m][nn], 0, 0, 0);
  }

  const int b = bh >> 6;
  const int h = bh & 63;
#pragma unroll
  for (int m = 0; m < 2; ++m) {
#pragma unroll
    for (int r = 0; r < 4; ++r) {
      float ls = __shfl(lsum[m], (lane & 48) + ((lane >> 4) << 2) + r);
      float inv = 1.0f / ls;
      int t = q0 + m * 16 + 4 * g + r;
#pragma unroll
      for (int nn = 0; nn < 2; ++nn) {
        float ov = o[m][nn][r] * inv;
        att[((size_t)(b * Tlen + t)) * 2048 + h * 32 + nn * 16 + l15] = (__bf16)ov;
      }
    }
  }
}

// ---------- launch ----------

extern "C" void kernel_launch(void* const* d_in, const int* in_sizes, int n_in,
                              void* d_out, int out_size, void* d_ws, size_t ws_size,
                              hipStream_t stream) {
  const float* x = (const float*)d_in[0];
  const float* pos = (const float*)d_in[1];
  const float* w_attn = (const float*)d_in[2];
  const float* w_proj = (const float*)d_in[3];
  float* out = (float*)d_out;

  char* ws = (char*)d_ws;
  size_t off = 0;
  auto alloc = [&](size_t bytes) {
    void* p = ws + off;
    off = (off + bytes + 255) & ~(size_t)255;
    return p;
  };
  __bf16* xb  = (__bf16*)alloc(2048ull * 2048 * 2);
  __bf16* waT = (__bf16*)alloc(6144ull * 2048 * 2);
  __bf16* wpT = (__bf16*)alloc(2048ull * 2048 * 2);
  __bf16* Qb  = (__bf16*)alloc(2ull * 64 * 1024 * 32 * 2);
  __bf16* Kb  = (__bf16*)alloc(2ull * 64 * 1024 * 32 * 2);
  __bf16* Vtb = (__bf16*)alloc(2ull * 64 * 32 * 1024 * 2);
  __bf16* att = (__bf16*)alloc(2048ull * 2048 * 2);
  float* cosT = (float*)alloc(1024ull * 32 * 4);
  float* sinT = (float*)alloc(1024ull * 32 * 4);

  k_cvt_bf16<<<2048, 256, 0, stream>>>(x, xb, 2048 * 2048);
  k_transpose_bf16<<<dim3(6144 / 64, 2048 / 64), 256, 0, stream>>>(w_attn, waT, 2048, 6144);
  k_transpose_bf16<<<dim3(2048 / 64, 2048 / 64), 256, 0, stream>>>(w_proj, wpT, 2048, 2048);
  k_sincos<<<128, 256, 0, stream>>>(pos, cosT, sinT);

  // qkv = xb @ waT^T with fused RoPE + layout (merged 2-phase/K-tile, 4 barriers)
  k_gemm8<1><<<dim3(6144 / 256, 2048 / 256), 512, 0, stream>>>(
      xb, waT, 2048, 6144, 2048, nullptr, Qb, Kb, Vtb, cosT, sinT);

  k_attn<<<dim3(8, 128), 256, 0, stream>>>(Qb, Kb, Vtb, att);

  // out = att @ wpT^T (2-phase 128^2 dbuf, R4 config)
  k_gemm<128, 128, 2, 2><<<dim3(2048 / 128, 2048 / 128), 256, 0, stream>>>(
      att, wpT, 2048, 2048, 2048, out);
}

// Round 9
// 177.374 us; speedup vs baseline: 1.0760x; 1.0760x over previous
//
#include <hip/hip_runtime.h>
#include <hip/hip_bf16.h>
#include <math.h>

typedef __attribute__((ext_vector_type(8))) __bf16 bf16x8;
typedef __attribute__((ext_vector_type(4))) __bf16 bf16x4;
typedef __attribute__((ext_vector_type(4))) float f32x4;

#define DEVINL static __device__ __forceinline__

static constexpr int Tlen = 1024;
static constexpr int HD = 32;

DEVINL void gload_lds16(const void* g, void* l) {
  __builtin_amdgcn_global_load_lds(
      (const __attribute__((address_space(1))) void*)g,
      (__attribute__((address_space(3))) void*)l, 16, 0, 0);
}

DEVINL unsigned short bfbits(float x) {
  __bf16 b = (__bf16)x;
  return __builtin_bit_cast(unsigned short, b);
}

// ---------- small staging kernels ----------

__global__ void k_cvt_bf16(const float* __restrict__ in, __bf16* __restrict__ out, int n) {
  int i = (blockIdx.x * blockDim.x + threadIdx.x) * 8;
  if (i >= n) return;
  const float4* p = (const float4*)(in + i);
  float4 a = p[0], b = p[1];
  bf16x8 v;
  v[0] = (__bf16)a.x; v[1] = (__bf16)a.y; v[2] = (__bf16)a.z; v[3] = (__bf16)a.w;
  v[4] = (__bf16)b.x; v[5] = (__bf16)b.y; v[6] = (__bf16)b.z; v[7] = (__bf16)b.w;
  *(bf16x8*)(out + i) = v;
}

// w[K][N] fp32 -> wt[N][K] bf16. 64x64 tile, float4 loads, bf16x4 stores.
__global__ void k_transpose_bf16(const float* __restrict__ w, __bf16* __restrict__ wt,
                                 int K, int N) {
  __shared__ float tile[64][65];
  const int n0 = blockIdx.x * 64;
  const int k0 = blockIdx.y * 64;
  const int tx = threadIdx.x & 15;
  const int ty = threadIdx.x >> 4;
#pragma unroll
  for (int i = 0; i < 4; ++i) {
    float4 v = *(const float4*)&w[(size_t)(k0 + ty + i * 16) * N + n0 + tx * 4];
    tile[ty + i * 16][tx * 4 + 0] = v.x;
    tile[ty + i * 16][tx * 4 + 1] = v.y;
    tile[ty + i * 16][tx * 4 + 2] = v.z;
    tile[ty + i * 16][tx * 4 + 3] = v.w;
  }
  __syncthreads();
#pragma unroll
  for (int i = 0; i < 4; ++i) {
    int n = ty + i * 16;
    bf16x4 s;
#pragma unroll
    for (int j = 0; j < 4; ++j) s[j] = (__bf16)tile[tx * 4 + j][n];
    *(bf16x4*)&wt[(size_t)(n0 + n) * K + k0 + tx * 4] = s;
  }
}

__global__ void k_sincos(const float* __restrict__ pos, float* __restrict__ cosT,
                         float* __restrict__ sinT) {
  int idx = blockIdx.x * blockDim.x + threadIdx.x;  // T*32
  int t = idx >> 5, d = idx & 31;
  float invf = powf(10000.0f, -(float)d * (1.0f / 32.0f));
  float ang = pos[t] * invf;
  cosT[idx] = cosf(ang);
  sinT[idx] = sinf(ang);
}

// ---------- 256x192 GEMM for qkv: grid 32x8 = 256 blocks = 1/CU, FULL coverage ----
// Same merged-2-phase schedule as R8 (perf-equivalent to 8-phase, measured).
// Staging units per K-tile: A0 (m-quadrants 0,2; 2 issues), B (whole, 3 issues),
// A1 (m-quadrants 1,3; 2 issues) = 7 issues/thread/K-tile.
// vmcnt ledger (steady state): issue order ... AB(kt-1):A1[kt](2), CD(kt-1):
// A0[kt+1]+B[kt+1](5), AB(kt):A1[kt+1](2), CD(kt):A0[kt+2]+B[kt+2](5).
//  - end AB(kt): need A1[kt] -> outstanding <= 5+2 = 7 -> vmcnt(7)
//  - end CD(kt): need A0[kt+1],B[kt+1] -> outstanding <= 2+5 = 7 -> vmcnt(7)
// Tail: CD(NT-2) end -> vmcnt(2); AB(NT-1) end -> vmcnt(0).
// XCD panel clustering: XCD x owns bx in {4x..4x+3} (B-panel 3MB, L2-resident,
// reused by 8 blocks) x by in {0..7}.
// MODE 1 epilogue: RoPE -> Q/K [B,H,T,32], V^T [B,H,32,T]. Handles q/k/v
// boundary mid-tile (sec per-lane; shfl unconditional before branch).
__launch_bounds__(512, 2)
__global__ void k_gemmqkv(const __bf16* __restrict__ A, const __bf16* __restrict__ Bt,
                          int M, int N, int K,
                          __bf16* __restrict__ Qo, __bf16* __restrict__ Ko,
                          __bf16* __restrict__ Vto, const float* __restrict__ cosT,
                          const float* __restrict__ sinT) {
  constexpr int BM = 256, BN = 192;
  __shared__ alignas(16) __bf16 As[2][BM * 64];
  __shared__ alignas(16) __bf16 Bs[2][BN * 64];

  const int tid = threadIdx.x;
  const int lane = tid & 63;
  const int wave = tid >> 6;            // 0..7
  const int wr = wave >> 2, wc = wave & 3;
  const int l15 = lane & 15;
  const int g = lane >> 4;              // 0..3

  // panel-clustered XCD swizzle: bid%8 = XCD; each XCD gets 4 bx cols x 8 by rows
  const int bid = blockIdx.y * gridDim.x + blockIdx.x;  // [0,256)
  const int x = bid & 7;
  const int u = bid >> 3;               // [0,32)
  const int bx = 4 * x + (u & 3);       // [0,32)
  const int by = u >> 2;                // [0,8)
  const int m0 = by * BM, n0 = bx * BN;

  f32x4 acc[8][3] = {};

  const int srcChunkElem = ((lane & 7) ^ (lane >> 3)) * 8;
  const int laneRow = lane >> 3;        // 0..7
  const int NT = K >> 6;

  // A half mh: rows [mh*64, mh*64+64) U [128+mh*64, 128+mh*64+64)
  auto stageA = [&](int buf, int kt, int mh) {
    const int k0 = kt << 6;
#pragma unroll
    for (int i = 0; i < 2; ++i) {
      int gi = i * 8 + wave;                                // 0..15
      int rowstart = ((gi >> 3) << 7) + (mh << 6) + ((gi & 7) << 3);
      gload_lds16(A + (size_t)(m0 + rowstart + laneRow) * K + k0 + srcChunkElem,
                  &As[buf][rowstart * 64]);
    }
  };
  // B whole tile: 192 rows = 3 issues x 64 rows
  auto stageB = [&](int buf, int kt) {
    const int k0 = kt << 6;
#pragma unroll
    for (int i = 0; i < 3; ++i) {
      int rowstart = i * 64 + wave * 8;
      gload_lds16(Bt + (size_t)(n0 + rowstart + laneRow) * K + k0 + srcChunkElem,
                  &Bs[buf][rowstart * 64]);
    }
  };

  // prologue: tile0 A0,B,A1 (7), tile1 A0,B (5); drain tile0 -> vmcnt(7)... 
  // order: A0(0),B(0),A1(0),A0(1),B(1): first AB needs A0(0),B(0) -> <= 2+5=7
  stageA(0, 0, 0); stageB(0, 0); stageA(0, 0, 1);
  if (NT > 1) {
    stageA(1, 1, 0); stageB(1, 1);
    asm volatile("s_waitcnt vmcnt(7)" ::: "memory");
  } else {
    asm volatile("s_waitcnt vmcnt(0)" ::: "memory");
  }
  __builtin_amdgcn_s_barrier();
  __builtin_amdgcn_sched_barrier(0);

  bf16x8 af[4][2], af2[4][2], bfv[3][2];

  for (int kt = 0; kt < NT; ++kt) {
    const int cur = kt & 1;
    const char* ab = (const char*)&As[cur][0];
    const char* bb = (const char*)&Bs[cur][0];

    // ---- phase AB: 14 ds_reads (A_mh0 + all B), 24 MFMA (m0..3, n0..2)
#pragma unroll
    for (int m = 0; m < 4; ++m)
#pragma unroll
      for (int hh = 0; hh < 2; ++hh) {
        int ar = wr * 128 + m * 16 + l15;
        int chunk = (4 * hh + g) ^ (lane & 7);
        af[m][hh] = *(const bf16x8*)(ab + ar * 128 + chunk * 16);
      }
#pragma unroll
    for (int n = 0; n < 3; ++n)
#pragma unroll
      for (int hh = 0; hh < 2; ++hh) {
        int br = wc * 48 + n * 16 + l15;
        int chunk = (4 * hh + g) ^ (lane & 7);
        bfv[n][hh] = *(const bf16x8*)(bb + br * 128 + chunk * 16);
      }
    if (kt + 1 < NT) stageA(cur ^ 1, kt + 1, 1);   // A1[kt+1] (2 gloads)
    __builtin_amdgcn_s_barrier();
    asm volatile("s_waitcnt lgkmcnt(0)" ::: "memory");
    __builtin_amdgcn_sched_barrier(0);
    __builtin_amdgcn_s_setprio(1);
#pragma unroll
    for (int hh = 0; hh < 2; ++hh)
#pragma unroll
      for (int m = 0; m < 4; ++m)
#pragma unroll
        for (int n = 0; n < 3; ++n)
          acc[m][n] = __builtin_amdgcn_mfma_f32_16x16x32_bf16(af[m][hh], bfv[n][hh], acc[m][n], 0, 0, 0);
    __builtin_amdgcn_s_setprio(0);
    __builtin_amdgcn_sched_barrier(0);
    if (kt + 1 < NT) {
      asm volatile("s_waitcnt vmcnt(7)" ::: "memory");   // A1[kt] resident for CD
    } else {
      asm volatile("s_waitcnt vmcnt(0)" ::: "memory");
    }
    __builtin_amdgcn_s_barrier();
    __builtin_amdgcn_sched_barrier(0);

    // ---- phase CD: 8 ds_reads (A_mh1), 24 MFMA (m4..7, n0..2); B held in regs
#pragma unroll
    for (int m = 0; m < 4; ++m)
#pragma unroll
      for (int hh = 0; hh < 2; ++hh) {
        int ar = wr * 128 + 64 + m * 16 + l15;
        int chunk = (4 * hh + g) ^ (lane & 7);
        af2[m][hh] = *(const bf16x8*)(ab + ar * 128 + chunk * 16);
      }
    if (kt + 2 < NT) {  // A0[kt+2],B[kt+2] (5 gloads) into buf cur
      stageA(cur, kt + 2, 0); stageB(cur, kt + 2);
    }
    __builtin_amdgcn_s_barrier();
    asm volatile("s_waitcnt lgkmcnt(0)" ::: "memory");
    __builtin_amdgcn_sched_barrier(0);
    __builtin_amdgcn_s_setprio(1);
#pragma unroll
    for (int hh = 0; hh < 2; ++hh)
#pragma unroll
      for (int m = 0; m < 4; ++m)
#pragma unroll
        for (int n = 0; n < 3; ++n)
          acc[m + 4][n] = __builtin_amdgcn_mfma_f32_16x16x32_bf16(af2[m][hh], bfv[n][hh], acc[m + 4][n], 0, 0, 0);
    __builtin_amdgcn_s_setprio(0);
    __builtin_amdgcn_sched_barrier(0);
    if (kt + 2 < NT) {
      asm volatile("s_waitcnt vmcnt(7)" ::: "memory");   // A0,B[kt+1] resident
    } else if (kt + 1 < NT) {
      asm volatile("s_waitcnt vmcnt(2)" ::: "memory");
    }
    if (kt + 1 < NT) {
      __builtin_amdgcn_s_barrier();
      __builtin_amdgcn_sched_barrier(0);
    }
  }

  // epilogue: RoPE + layout
#pragma unroll
  for (int m = 0; m < 8; ++m) {
    int row_l = wr * 128 + m * 16 + (g << 2);
#pragma unroll
    for (int n = 0; n < 3; ++n) {
      int col = n0 + wc * 48 + n * 16 + l15;
#pragma unroll
      for (int r = 0; r < 4; ++r) {
        int row = m0 + row_l + r;
        float v = acc[m][n][r];
        int b = row >> 10, t = row & 1023;
        int sec = col >> 11;           // 0=q,1=k,2=v (per-lane; may split mid-tile)
        int c2 = col & 2047;
        int h = c2 >> 5, d = c2 & 31;
        float partner = __shfl_xor(v, 1);  // unconditional, before divergence
        if (sec < 2) {
          float rot = (d & 1) ? partner : -partner;
          float cs = cosT[t * 32 + d], sn = sinT[t * 32 + d];
          float o = v * cs + rot * sn;
          if (sec == 0) o *= 0.17677669529663687f;  // fold 1/sqrt(hd) into Q
          __bf16* dst = sec ? Ko : Qo;
          dst[((size_t)((b << 6) | h) * Tlen + t) * HD + d] = (__bf16)o;
        } else {
          Vto[((size_t)((b << 6) | h) * HD + d) * Tlen + t] = (__bf16)v;
        }
      }
    }
  }
}

// ---------- 2-phase 128x128 GEMM (for the projection; R4 config) ----------
template <int BM, int BN, int WM, int WN>
__launch_bounds__(WM * WN * 64)
__global__ void k_gemm(const __bf16* __restrict__ A, const __bf16* __restrict__ Bt,
                       int M, int N, int K, float* __restrict__ Cout) {
  constexpr int T = WM * WN * 64;
  constexpr int M_rep = BM / (WM * 16);
  constexpr int N_rep = BN / (WN * 16);
  constexpr int nA = (BM * 128) / (T * 16);
  constexpr int nB = (BN * 128) / (T * 16);
  constexpr int ROWS_PER_ISSUE = T / 8;

  __shared__ alignas(16) __bf16 As[2][BM * 64];
  __shared__ alignas(16) __bf16 Bs[2][BN * 64];

  const int tid = threadIdx.x;
  const int lane = tid & 63;
  const int wave = tid >> 6;
  const int wr = wave / WN, wc = wave % WN;
  const int l15 = lane & 15;

  const int nwg = gridDim.x * gridDim.y;
  const int bid = blockIdx.y * gridDim.x + blockIdx.x;
  const int cpx = nwg >> 3;
  const int tswz = (bid & 7) * cpx + (bid >> 3);
  const int bx = tswz % gridDim.x, by = tswz / gridDim.x;
  const int m0 = by * BM, n0 = bx * BN;

  f32x4 acc[M_rep][N_rep] = {};

  const int srcChunkElem = ((lane & 7) ^ (lane >> 3)) * 8;
  const int rowInWave = wave * 8 + (lane >> 3);

  const int NT = K >> 6;

  auto stage = [&](int buf, int kt) {
    const int k0 = kt << 6;
#pragma unroll
    for (int i = 0; i < nA; ++i) {
      int row = i * ROWS_PER_ISSUE + rowInWave;
      gload_lds16(A + (size_t)(m0 + row) * K + k0 + srcChunkElem,
                  &As[buf][(i * T + wave * 64) * 8]);
    }
#pragma unroll
    for (int i = 0; i < nB; ++i) {
      int row = i * ROWS_PER_ISSUE + rowInWave;
      gload_lds16(Bt + (size_t)(n0 + row) * K + k0 + srcChunkElem,
                  &Bs[buf][(i * T + wave * 64) * 8]);
    }
  };

  stage(0, 0);

  for (int kt = 0; kt < NT; ++kt) {
    const int cur = kt & 1;
    if (kt + 1 < NT) {
      stage(cur ^ 1, kt + 1);
      asm volatile("s_waitcnt vmcnt(8)" ::: "memory");
    } else {
      asm volatile("s_waitcnt vmcnt(0)" ::: "memory");
    }
    __builtin_amdgcn_s_barrier();
    __builtin_amdgcn_sched_barrier(0);

    const char* ab = (const char*)&As[cur][0];
    const char* bb = (const char*)&Bs[cur][0];
#pragma unroll
    for (int hh = 0; hh < 2; ++hh) {
      bf16x8 af[M_rep], bfv[N_rep];
#pragma unroll
      for (int m = 0; m < M_rep; ++m) {
        int ar = wr * (M_rep * 16) + m * 16 + l15;
        int chunk = ((4 * hh + (lane >> 4)) ^ (lane & 7));
        af[m] = *(const bf16x8*)(ab + ar * 128 + chunk * 16);
      }
#pragma unroll
      for (int n = 0; n < N_rep; ++n) {
        int br = wc * (N_rep * 16) + n * 16 + l15;
        int chunk = ((4 * hh + (lane >> 4)) ^ (lane & 7));
        bfv[n] = *(const bf16x8*)(bb + br * 128 + chunk * 16);
      }
      __builtin_amdgcn_s_setprio(1);
#pragma unroll
      for (int m = 0; m < M_rep; ++m)
#pragma unroll
        for (int n = 0; n < N_rep; ++n)
          acc[m][n] = __builtin_amdgcn_mfma_f32_16x16x32_bf16(af[m], bfv[n], acc[m][n], 0, 0, 0);
      __builtin_amdgcn_s_setprio(0);
    }
    __builtin_amdgcn_sched_barrier(0);
    __builtin_amdgcn_s_barrier();
  }

#pragma unroll
  for (int m = 0; m < M_rep; ++m) {
    int row_l = wr * (M_rep * 16) + m * 16 + ((lane >> 4) << 2);
#pragma unroll
    for (int n = 0; n < N_rep; ++n) {
      int col = n0 + wc * (N_rep * 16) + n * 16 + l15;
#pragma unroll
      for (int r = 0; r < 4; ++r) {
        int row = m0 + row_l + r;
        Cout[(size_t)row * N + col] = acc[m][n][r];
      }
    }
  }
}

// ---------- flash attention: swapped QK^T, KVBLK=64, static softmax ----------
__launch_bounds__(256)
__global__ void k_attn(const __bf16* __restrict__ Q, const __bf16* __restrict__ Kmat,
                       const __bf16* __restrict__ Vt, __bf16* __restrict__ att) {
  __shared__ alignas(16) __bf16 P[4][32 * 72];
  const int tid = threadIdx.x;
  const int lane = tid & 63;
  const int w = tid >> 6;

  const int orig = blockIdx.y * gridDim.x + blockIdx.x;  // [0,1024)
  const int idx = orig >> 3;                             // [0,128)
  const int bh = (orig & 7) * 16 + (idx >> 3);           // 16 heads per XCD
  const int j = idx & 7;                                 // [0,8)

  const int qt = (w == 0) ? 2 * j : (w == 1) ? 2 * j + 1 : (w == 2) ? 30 - 2 * j : 31 - 2 * j;
  const int q0 = qt * 32;

  const __bf16* Qb = Q + (size_t)bh * Tlen * HD;
  const __bf16* Kb = Kmat + (size_t)bh * Tlen * HD;
  const __bf16* Vb = Vt + (size_t)bh * HD * Tlen;
  __bf16* Pw = &P[w][0];

  const int l15 = lane & 15;
  const int g = lane >> 4;
  const int lk8 = g * 8;

  bf16x8 qf[2];
#pragma unroll
  for (int m = 0; m < 2; ++m)
    qf[m] = *(const bf16x8*)(Qb + (size_t)(q0 + m * 16 + l15) * HD + lk8);

  f32x4 o[2][2] = {};
  float lsum[2] = {0.f, 0.f};

  const int nfull = q0 >> 6;

  for (int kt = 0; kt <= nfull; ++kt) {
    const int k0 = kt * 64;
    bf16x8 kf[4];
#pragma unroll
    for (int n = 0; n < 4; ++n)
      kf[n] = *(const bf16x8*)(Kb + (size_t)(k0 + n * 16 + l15) * HD + lk8);

    f32x4 st[4][2] = {};
#pragma unroll
    for (int n = 0; n < 4; ++n)
#pragma unroll
      for (int m = 0; m < 2; ++m)
        st[n][m] = __builtin_amdgcn_mfma_f32_16x16x32_bf16(kf[n], qf[m], st[n][m], 0, 0, 0);

    bf16x8 vf[2][2];
#pragma unroll
    for (int nn = 0; nn < 2; ++nn)
#pragma unroll
      for (int c = 0; c < 2; ++c)
        vf[nn][c] = *(const bf16x8*)(Vb + (size_t)(nn * 16 + l15) * Tlen + k0 + c * 32 + lk8);

    if (kt == nfull) {
#pragma unroll
      for (int n = 0; n < 4; ++n)
#pragma unroll
        for (int m = 0; m < 2; ++m)
#pragma unroll
          for (int r = 0; r < 4; ++r) {
            int kk = k0 + n * 16 + 4 * g + r;
            int qq = q0 + m * 16 + l15;
            if (kk > qq) st[n][m][r] = -1e30f;
          }
    }

#pragma unroll
    for (int m = 0; m < 2; ++m) {
      float p[16];
      float ps = 0.f;
#pragma unroll
      for (int n = 0; n < 4; ++n)
#pragma unroll
        for (int r = 0; r < 4; ++r) {
          float pv = __expf(st[n][m][r]);
          p[n * 4 + r] = pv;
          ps += pv;
        }
      ps += __shfl_xor(ps, 16);
      ps += __shfl_xor(ps, 32);
      lsum[m] += ps;

#pragma unroll
      for (int n = 0; n < 4; ++n) {
        unsigned int u0 = ((unsigned int)bfbits(p[n * 4 + 1]) << 16) | bfbits(p[n * 4 + 0]);
        unsigned int u1 = ((unsigned int)bfbits(p[n * 4 + 3]) << 16) | bfbits(p[n * 4 + 2]);
        int base = (m * 16 + l15) * 72 + n * 16 + 4 * g;
        *(unsigned int*)&Pw[base] = u0;
        *(unsigned int*)&Pw[base + 2] = u1;
      }
    }

    bf16x8 pa[2][2];
#pragma unroll
    for (int m = 0; m < 2; ++m)
#pragma unroll
      for (int c = 0; c < 2; ++c)
        pa[m][c] = *(const bf16x8*)&Pw[(m * 16 + l15) * 72 + c * 32 + lk8];

#pragma unroll
    for (int m = 0; m < 2; ++m)
#pragma unroll
      for (int nn = 0; nn < 2; ++nn)
#pragma unroll
        for (int c = 0; c < 2; ++c)
          o[m][nn] = __builtin_amdgcn_mfma_f32_16x16x32_bf16(pa[m][c], vf[nn][c], o[m][nn], 0, 0, 0);
  }

  const int b = bh >> 6;
  const int h = bh & 63;
#pragma unroll
  for (int m = 0; m < 2; ++m) {
#pragma unroll
    for (int r = 0; r < 4; ++r) {
      float ls = __shfl(lsum[m], (lane & 48) + ((lane >> 4) << 2) + r);
      float inv = 1.0f / ls;
      int t = q0 + m * 16 + 4 * g + r;
#pragma unroll
      for (int nn = 0; nn < 2; ++nn) {
        float ov = o[m][nn][r] * inv;
        att[((size_t)(b * Tlen + t)) * 2048 + h * 32 + nn * 16 + l15] = (__bf16)ov;
      }
    }
  }
}

// ---------- launch ----------

extern "C" void kernel_launch(void* const* d_in, const int* in_sizes, int n_in,
                              void* d_out, int out_size, void* d_ws, size_t ws_size,
                              hipStream_t stream) {
  const float* x = (const float*)d_in[0];
  const float* pos = (const float*)d_in[1];
  const float* w_attn = (const float*)d_in[2];
  const float* w_proj = (const float*)d_in[3];
  float* out = (float*)d_out;

  char* ws = (char*)d_ws;
  size_t off = 0;
  auto alloc = [&](size_t bytes) {
    void* p = ws + off;
    off = (off + bytes + 255) & ~(size_t)255;
    return p;
  };
  __bf16* xb  = (__bf16*)alloc(2048ull * 2048 * 2);
  __bf16* waT = (__bf16*)alloc(6144ull * 2048 * 2);
  __bf16* wpT = (__bf16*)alloc(2048ull * 2048 * 2);
  __bf16* Qb  = (__bf16*)alloc(2ull * 64 * 1024 * 32 * 2);
  __bf16* Kb  = (__bf16*)alloc(2ull * 64 * 1024 * 32 * 2);
  __bf16* Vtb = (__bf16*)alloc(2ull * 64 * 32 * 1024 * 2);
  __bf16* att = (__bf16*)alloc(2048ull * 2048 * 2);
  float* cosT = (float*)alloc(1024ull * 32 * 4);
  float* sinT = (float*)alloc(1024ull * 32 * 4);

  k_cvt_bf16<<<2048, 256, 0, stream>>>(x, xb, 2048 * 2048);
  k_transpose_bf16<<<dim3(6144 / 64, 2048 / 64), 256, 0, stream>>>(w_attn, waT, 2048, 6144);
  k_transpose_bf16<<<dim3(2048 / 64, 2048 / 64), 256, 0, stream>>>(w_proj, wpT, 2048, 2048);
  k_sincos<<<128, 256, 0, stream>>>(pos, cosT, sinT);

  // qkv = xb @ waT^T with fused RoPE + layout (256x192 tile, 256 blocks = 1/CU)
  k_gemmqkv<<<dim3(6144 / 192, 2048 / 256), 512, 0, stream>>>(
      xb, waT, 2048, 6144, 2048, Qb, Kb, Vtb, cosT, sinT);

  k_attn<<<dim3(8, 128), 256, 0, stream>>>(Qb, Kb, Vtb, att);

  // out = att @ wpT^T (2-phase 128^2 dbuf, R4 config)
  k_gemm<128, 128, 2, 2><<<dim3(2048 / 128, 2048 / 128), 256, 0, stream>>>(
      att, wpT, 2048, 2048, 2048, out);
}

// Round 10
// 171.927 us; speedup vs baseline: 1.1101x; 1.0317x over previous
//
#include <hip/hip_runtime.h>
#include <hip/hip_bf16.h>
#include <math.h>

typedef __attribute__((ext_vector_type(8))) __bf16 bf16x8;
typedef __attribute__((ext_vector_type(4))) __bf16 bf16x4;
typedef __attribute__((ext_vector_type(4))) float f32x4;

#define DEVINL static __device__ __forceinline__

static constexpr int Tlen = 1024;
static constexpr int HD = 32;

DEVINL void gload_lds16(const void* g, void* l) {
  __builtin_amdgcn_global_load_lds(
      (const __attribute__((address_space(1))) void*)g,
      (__attribute__((address_space(3))) void*)l, 16, 0, 0);
}

DEVINL unsigned short bfbits(float x) {
  __bf16 b = (__bf16)x;
  return __builtin_bit_cast(unsigned short, b);
}

// ---------- small staging kernels ----------

__global__ void k_cvt_bf16(const float* __restrict__ in, __bf16* __restrict__ out, int n) {
  int i = (blockIdx.x * blockDim.x + threadIdx.x) * 8;
  if (i >= n) return;
  const float4* p = (const float4*)(in + i);
  float4 a = p[0], b = p[1];
  bf16x8 v;
  v[0] = (__bf16)a.x; v[1] = (__bf16)a.y; v[2] = (__bf16)a.z; v[3] = (__bf16)a.w;
  v[4] = (__bf16)b.x; v[5] = (__bf16)b.y; v[6] = (__bf16)b.z; v[7] = (__bf16)b.w;
  *(bf16x8*)(out + i) = v;
}

// w[K][N] fp32 -> wt[N][K] bf16. 64x64 tile, float4 loads, bf16x4 stores.
__global__ void k_transpose_bf16(const float* __restrict__ w, __bf16* __restrict__ wt,
                                 int K, int N) {
  __shared__ float tile[64][65];
  const int n0 = blockIdx.x * 64;
  const int k0 = blockIdx.y * 64;
  const int tx = threadIdx.x & 15;
  const int ty = threadIdx.x >> 4;
#pragma unroll
  for (int i = 0; i < 4; ++i) {
    float4 v = *(const float4*)&w[(size_t)(k0 + ty + i * 16) * N + n0 + tx * 4];
    tile[ty + i * 16][tx * 4 + 0] = v.x;
    tile[ty + i * 16][tx * 4 + 1] = v.y;
    tile[ty + i * 16][tx * 4 + 2] = v.z;
    tile[ty + i * 16][tx * 4 + 3] = v.w;
  }
  __syncthreads();
#pragma unroll
  for (int i = 0; i < 4; ++i) {
    int n = ty + i * 16;
    bf16x4 s;
#pragma unroll
    for (int j = 0; j < 4; ++j) s[j] = (__bf16)tile[tx * 4 + j][n];
    *(bf16x4*)&wt[(size_t)(n0 + n) * K + k0 + tx * 4] = s;
  }
}

__global__ void k_sincos(const float* __restrict__ pos, float* __restrict__ cosT,
                         float* __restrict__ sinT) {
  int idx = blockIdx.x * blockDim.x + threadIdx.x;  // T*32
  int t = idx >> 5, d = idx & 31;
  float invf = powf(10000.0f, -(float)d * (1.0f / 32.0f));
  float ang = pos[t] * invf;
  cosT[idx] = cosf(ang);
  sinT[idx] = sinf(ang);
}

// ---------- 256x192 GEMM for qkv: 256 blocks = 1/CU, unpinned scheduler ----------
// R9 geometry (full coverage, panel-clustered XCD swizzle) + R10 change:
// NO sched_barrier(0), NO manual lgkmcnt (compiler emits fine-grained waits,
// m97/m141 evidence), 2 barriers + 1 vmcnt per K-tile.
// Per K-tile: read af(A_mh0,8) + bfv(B,6) + af2(A_mh1,8) [tile kt fully
// resident at phase start], stage A1[kt+1]; MFMA-AB; mid-barrier (protects
// mh0/B overwrite); stage A0/B[kt+2] into buf[cur]; MFMA-CD; vmcnt(5); barrier.
// vmcnt ledger: at CD(kt) end outstanding = A1[kt+1](2) + A0/B[kt+2](5) = 7;
// newest 5 = A0/B[kt+2] -> vmcnt(5) drains ALL of tile kt+1. Tail:
// kt=NT-2 -> vmcnt(0); kt=NT-1 -> no waits.
__launch_bounds__(512, 2)
__global__ void k_gemmqkv(const __bf16* __restrict__ A, const __bf16* __restrict__ Bt,
                          int M, int N, int K,
                          __bf16* __restrict__ Qo, __bf16* __restrict__ Ko,
                          __bf16* __restrict__ Vto, const float* __restrict__ cosT,
                          const float* __restrict__ sinT) {
  constexpr int BM = 256, BN = 192;
  __shared__ alignas(16) __bf16 As[2][BM * 64];
  __shared__ alignas(16) __bf16 Bs[2][BN * 64];

  const int tid = threadIdx.x;
  const int lane = tid & 63;
  const int wave = tid >> 6;            // 0..7
  const int wr = wave >> 2, wc = wave & 3;
  const int l15 = lane & 15;
  const int g = lane >> 4;              // 0..3

  // panel-clustered XCD swizzle: bid%8 = XCD; each XCD gets 4 bx cols x 8 by rows
  const int bid = blockIdx.y * gridDim.x + blockIdx.x;  // [0,256)
  const int x = bid & 7;
  const int u = bid >> 3;               // [0,32)
  const int bx = 4 * x + (u & 3);       // [0,32)
  const int by = u >> 2;                // [0,8)
  const int m0 = by * BM, n0 = bx * BN;

  f32x4 acc[8][3] = {};

  const int srcChunkElem = ((lane & 7) ^ (lane >> 3)) * 8;
  const int laneRow = lane >> 3;        // 0..7
  const int NT = K >> 6;

  auto stageA = [&](int buf, int kt, int mh) {
    const int k0 = kt << 6;
#pragma unroll
    for (int i = 0; i < 2; ++i) {
      int gi = i * 8 + wave;                                // 0..15
      int rowstart = ((gi >> 3) << 7) + (mh << 6) + ((gi & 7) << 3);
      gload_lds16(A + (size_t)(m0 + rowstart + laneRow) * K + k0 + srcChunkElem,
                  &As[buf][rowstart * 64]);
    }
  };
  auto stageB = [&](int buf, int kt) {
    const int k0 = kt << 6;
#pragma unroll
    for (int i = 0; i < 3; ++i) {
      int rowstart = i * 64 + wave * 8;
      gload_lds16(Bt + (size_t)(n0 + rowstart + laneRow) * K + k0 + srcChunkElem,
                  &Bs[buf][rowstart * 64]);
    }
  };

  // prologue: tile0 complete (7), tile1 A0+B (5); vmcnt(5) -> tile0 resident
  stageA(0, 0, 0); stageB(0, 0); stageA(0, 0, 1);
  if (NT > 1) {
    stageA(1, 1, 0); stageB(1, 1);
    asm volatile("s_waitcnt vmcnt(5)" ::: "memory");
  } else {
    asm volatile("s_waitcnt vmcnt(0)" ::: "memory");
  }
  __builtin_amdgcn_s_barrier();

  bf16x8 af[4][2], af2[4][2], bfv[3][2];

  for (int kt = 0; kt < NT; ++kt) {
    const int cur = kt & 1;
    const char* ab = (const char*)&As[cur][0];
    const char* bb = (const char*)&Bs[cur][0];

    // all of tile kt is resident: read AB regs AND CD regs up front;
    // compiler schedules lgkmcnt so af2 reads overlap MFMA-AB.
#pragma unroll
    for (int m = 0; m < 4; ++m)
#pragma unroll
      for (int hh = 0; hh < 2; ++hh) {
        int ar = wr * 128 + m * 16 + l15;
        int chunk = (4 * hh + g) ^ (lane & 7);
        af[m][hh] = *(const bf16x8*)(ab + ar * 128 + chunk * 16);
      }
#pragma unroll
    for (int n = 0; n < 3; ++n)
#pragma unroll
      for (int hh = 0; hh < 2; ++hh) {
        int br = wc * 48 + n * 16 + l15;
        int chunk = (4 * hh + g) ^ (lane & 7);
        bfv[n][hh] = *(const bf16x8*)(bb + br * 128 + chunk * 16);
      }
#pragma unroll
    for (int m = 0; m < 4; ++m)
#pragma unroll
      for (int hh = 0; hh < 2; ++hh) {
        int ar = wr * 128 + 64 + m * 16 + l15;
        int chunk = (4 * hh + g) ^ (lane & 7);
        af2[m][hh] = *(const bf16x8*)(ab + ar * 128 + chunk * 16);
      }
    if (kt + 1 < NT) stageA(cur ^ 1, kt + 1, 1);   // A1[kt+1] (2 gloads)

    __builtin_amdgcn_s_setprio(1);
#pragma unroll
    for (int hh = 0; hh < 2; ++hh)
#pragma unroll
      for (int m = 0; m < 4; ++m)
#pragma unroll
        for (int n = 0; n < 3; ++n)
          acc[m][n] = __builtin_amdgcn_mfma_f32_16x16x32_bf16(af[m][hh], bfv[n][hh], acc[m][n], 0, 0, 0);
    __builtin_amdgcn_s_setprio(0);

    // mid-barrier: all waves' reads of A_mh0/B[cur] issued -> safe to overwrite
    __builtin_amdgcn_s_barrier();
    if (kt + 2 < NT) {  // A0[kt+2],B[kt+2] (5 gloads) into buf cur
      stageA(cur, kt + 2, 0); stageB(cur, kt + 2);
    }

    __builtin_amdgcn_s_setprio(1);
#pragma unroll
    for (int hh = 0; hh < 2; ++hh)
#pragma unroll
      for (int m = 0; m < 4; ++m)
#pragma unroll
        for (int n = 0; n < 3; ++n)
          acc[m + 4][n] = __builtin_amdgcn_mfma_f32_16x16x32_bf16(af2[m][hh], bfv[n][hh], acc[m + 4][n], 0, 0, 0);
    __builtin_amdgcn_s_setprio(0);

    if (kt + 2 < NT) {
      asm volatile("s_waitcnt vmcnt(5)" ::: "memory");   // tile kt+1 fully resident
    } else if (kt + 1 < NT) {
      asm volatile("s_waitcnt vmcnt(0)" ::: "memory");
    }
    if (kt + 1 < NT) __builtin_amdgcn_s_barrier();
  }

  // epilogue: RoPE + layout
#pragma unroll
  for (int m = 0; m < 8; ++m) {
    int row_l = wr * 128 + m * 16 + (g << 2);
#pragma unroll
    for (int n = 0; n < 3; ++n) {
      int col = n0 + wc * 48 + n * 16 + l15;
#pragma unroll
      for (int r = 0; r < 4; ++r) {
        int row = m0 + row_l + r;
        float v = acc[m][n][r];
        int b = row >> 10, t = row & 1023;
        int sec = col >> 11;           // 0=q,1=k,2=v (per-lane; may split mid-tile)
        int c2 = col & 2047;
        int h = c2 >> 5, d = c2 & 31;
        float partner = __shfl_xor(v, 1);  // unconditional, before divergence
        if (sec < 2) {
          float rot = (d & 1) ? partner : -partner;
          float cs = cosT[t * 32 + d], sn = sinT[t * 32 + d];
          float o = v * cs + rot * sn;
          if (sec == 0) o *= 0.17677669529663687f;  // fold 1/sqrt(hd) into Q
          __bf16* dst = sec ? Ko : Qo;
          dst[((size_t)((b << 6) | h) * Tlen + t) * HD + d] = (__bf16)o;
        } else {
          Vto[((size_t)((b << 6) | h) * HD + d) * Tlen + t] = (__bf16)v;
        }
      }
    }
  }
}

// ---------- 2-phase 128x128 GEMM (projection); sched_barriers removed ----------
template <int BM, int BN, int WM, int WN>
__launch_bounds__(WM * WN * 64)
__global__ void k_gemm(const __bf16* __restrict__ A, const __bf16* __restrict__ Bt,
                       int M, int N, int K, float* __restrict__ Cout) {
  constexpr int T = WM * WN * 64;
  constexpr int M_rep = BM / (WM * 16);
  constexpr int N_rep = BN / (WN * 16);
  constexpr int nA = (BM * 128) / (T * 16);
  constexpr int nB = (BN * 128) / (T * 16);
  constexpr int ROWS_PER_ISSUE = T / 8;

  __shared__ alignas(16) __bf16 As[2][BM * 64];
  __shared__ alignas(16) __bf16 Bs[2][BN * 64];

  const int tid = threadIdx.x;
  const int lane = tid & 63;
  const int wave = tid >> 6;
  const int wr = wave / WN, wc = wave % WN;
  const int l15 = lane & 15;

  const int nwg = gridDim.x * gridDim.y;
  const int bid = blockIdx.y * gridDim.x + blockIdx.x;
  const int cpx = nwg >> 3;
  const int tswz = (bid & 7) * cpx + (bid >> 3);
  const int bx = tswz % gridDim.x, by = tswz / gridDim.x;
  const int m0 = by * BM, n0 = bx * BN;

  f32x4 acc[M_rep][N_rep] = {};

  const int srcChunkElem = ((lane & 7) ^ (lane >> 3)) * 8;
  const int rowInWave = wave * 8 + (lane >> 3);

  const int NT = K >> 6;

  auto stage = [&](int buf, int kt) {
    const int k0 = kt << 6;
#pragma unroll
    for (int i = 0; i < nA; ++i) {
      int row = i * ROWS_PER_ISSUE + rowInWave;
      gload_lds16(A + (size_t)(m0 + row) * K + k0 + srcChunkElem,
                  &As[buf][(i * T + wave * 64) * 8]);
    }
#pragma unroll
    for (int i = 0; i < nB; ++i) {
      int row = i * ROWS_PER_ISSUE + rowInWave;
      gload_lds16(Bt + (size_t)(n0 + row) * K + k0 + srcChunkElem,
                  &Bs[buf][(i * T + wave * 64) * 8]);
    }
  };

  stage(0, 0);

  for (int kt = 0; kt < NT; ++kt) {
    const int cur = kt & 1;
    if (kt + 1 < NT) {
      stage(cur ^ 1, kt + 1);
      asm volatile("s_waitcnt vmcnt(8)" ::: "memory");
    } else {
      asm volatile("s_waitcnt vmcnt(0)" ::: "memory");
    }
    __builtin_amdgcn_s_barrier();

    const char* ab = (const char*)&As[cur][0];
    const char* bb = (const char*)&Bs[cur][0];
#pragma unroll
    for (int hh = 0; hh < 2; ++hh) {
      bf16x8 af[M_rep], bfv[N_rep];
#pragma unroll
      for (int m = 0; m < M_rep; ++m) {
        int ar = wr * (M_rep * 16) + m * 16 + l15;
        int chunk = ((4 * hh + (lane >> 4)) ^ (lane & 7));
        af[m] = *(const bf16x8*)(ab + ar * 128 + chunk * 16);
      }
#pragma unroll
      for (int n = 0; n < N_rep; ++n) {
        int br = wc * (N_rep * 16) + n * 16 + l15;
        int chunk = ((4 * hh + (lane >> 4)) ^ (lane & 7));
        bfv[n] = *(const bf16x8*)(bb + br * 128 + chunk * 16);
      }
      __builtin_amdgcn_s_setprio(1);
#pragma unroll
      for (int m = 0; m < M_rep; ++m)
#pragma unroll
        for (int n = 0; n < N_rep; ++n)
          acc[m][n] = __builtin_amdgcn_mfma_f32_16x16x32_bf16(af[m], bfv[n], acc[m][n], 0, 0, 0);
      __builtin_amdgcn_s_setprio(0);
    }
    __builtin_amdgcn_s_barrier();
  }

#pragma unroll
  for (int m = 0; m < M_rep; ++m) {
    int row_l = wr * (M_rep * 16) + m * 16 + ((lane >> 4) << 2);
#pragma unroll
    for (int n = 0; n < N_rep; ++n) {
      int col = n0 + wc * (N_rep * 16) + n * 16 + l15;
#pragma unroll
      for (int r = 0; r < 4; ++r) {
        int row = m0 + row_l + r;
        Cout[(size_t)row * N + col] = acc[m][n][r];
      }
    }
  }
}

// ---------- flash attention: swapped QK^T, KVBLK=64, static softmax ----------
__launch_bounds__(256)
__global__ void k_attn(const __bf16* __restrict__ Q, const __bf16* __restrict__ Kmat,
                       const __bf16* __restrict__ Vt, __bf16* __restrict__ att) {
  __shared__ alignas(16) __bf16 P[4][32 * 72];
  const int tid = threadIdx.x;
  const int lane = tid & 63;
  const int w = tid >> 6;

  const int orig = blockIdx.y * gridDim.x + blockIdx.x;  // [0,1024)
  const int idx = orig >> 3;                             // [0,128)
  const int bh = (orig & 7) * 16 + (idx >> 3);           // 16 heads per XCD
  const int j = idx & 7;                                 // [0,8)

  const int qt = (w == 0) ? 2 * j : (w == 1) ? 2 * j + 1 : (w == 2) ? 30 - 2 * j : 31 - 2 * j;
  const int q0 = qt * 32;

  const __bf16* Qb = Q + (size_t)bh * Tlen * HD;
  const __bf16* Kb = Kmat + (size_t)bh * Tlen * HD;
  const __bf16* Vb = Vt + (size_t)bh * HD * Tlen;
  __bf16* Pw = &P[w][0];

  const int l15 = lane & 15;
  const int g = lane >> 4;
  const int lk8 = g * 8;

  bf16x8 qf[2];
#pragma unroll
  for (int m = 0; m < 2; ++m)
    qf[m] = *(const bf16x8*)(Qb + (size_t)(q0 + m * 16 + l15) * HD + lk8);

  f32x4 o[2][2] = {};
  float lsum[2] = {0.f, 0.f};

  const int nfull = q0 >> 6;

  for (int kt = 0; kt <= nfull; ++kt) {
    const int k0 = kt * 64;
    bf16x8 kf[4];
#pragma unroll
    for (int n = 0; n < 4; ++n)
      kf[n] = *(const bf16x8*)(Kb + (size_t)(k0 + n * 16 + l15) * HD + lk8);

    f32x4 st[4][2] = {};
#pragma unroll
    for (int n = 0; n < 4; ++n)
#pragma unroll
      for (int m = 0; m < 2; ++m)
        st[n][m] = __builtin_amdgcn_mfma_f32_16x16x32_bf16(kf[n], qf[m], st[n][m], 0, 0, 0);

    bf16x8 vf[2][2];
#pragma unroll
    for (int nn = 0; nn < 2; ++nn)
#pragma unroll
      for (int c = 0; c < 2; ++c)
        vf[nn][c] = *(const bf16x8*)(Vb + (size_t)(nn * 16 + l15) * Tlen + k0 + c * 32 + lk8);

    if (kt == nfull) {
#pragma unroll
      for (int n = 0; n < 4; ++n)
#pragma unroll
        for (int m = 0; m < 2; ++m)
#pragma unroll
          for (int r = 0; r < 4; ++r) {
            int kk = k0 + n * 16 + 4 * g + r;
            int qq = q0 + m * 16 + l15;
            if (kk > qq) st[n][m][r] = -1e30f;
          }
    }

#pragma unroll
    for (int m = 0; m < 2; ++m) {
      float p[16];
      float ps = 0.f;
#pragma unroll
      for (int n = 0; n < 4; ++n)
#pragma unroll
        for (int r = 0; r < 4; ++r) {
          float pv = __expf(st[n][m][r]);
          p[n * 4 + r] = pv;
          ps += pv;
        }
      ps += __shfl_xor(ps, 16);
      ps += __shfl_xor(ps, 32);
      lsum[m] += ps;

#pragma unroll
      for (int n = 0; n < 4; ++n) {
        unsigned int u0 = ((unsigned int)bfbits(p[n * 4 + 1]) << 16) | bfbits(p[n * 4 + 0]);
        unsigned int u1 = ((unsigned int)bfbits(p[n * 4 + 3]) << 16) | bfbits(p[n * 4 + 2]);
        int base = (m * 16 + l15) * 72 + n * 16 + 4 * g;
        *(unsigned int*)&Pw[base] = u0;
        *(unsigned int*)&Pw[base + 2] = u1;
      }
    }

    bf16x8 pa[2][2];
#pragma unroll
    for (int m = 0; m < 2; ++m)
#pragma unroll
      for (int c = 0; c < 2; ++c)
        pa[m][c] = *(const bf16x8*)&Pw[(m * 16 + l15) * 72 + c * 32 + lk8];

#pragma unroll
    for (int m = 0; m < 2; ++m)
#pragma unroll
      for (int nn = 0; nn < 2; ++nn)
#pragma unroll
        for (int c = 0; c < 2; ++c)
          o[m][nn] = __builtin_amdgcn_mfma_f32_16x16x32_bf16(pa[m][c], vf[nn][c], o[m][nn], 0, 0, 0);
  }

  const int b = bh >> 6;
  const int h = bh & 63;
#pragma unroll
  for (int m = 0; m < 2; ++m) {
#pragma unroll
    for (int r = 0; r < 4; ++r) {
      float ls = __shfl(lsum[m], (lane & 48) + ((lane >> 4) << 2) + r);
      float inv = 1.0f / ls;
      int t = q0 + m * 16 + 4 * g + r;
#pragma unroll
      for (int nn = 0; nn < 2; ++nn) {
        float ov = o[m][nn][r] * inv;
        att[((size_t)(b * Tlen + t)) * 2048 + h * 32 + nn * 16 + l15] = (__bf16)ov;
      }
    }
  }
}

// ---------- launch ----------

extern "C" void kernel_launch(void* const* d_in, const int* in_sizes, int n_in,
                              void* d_out, int out_size, void* d_ws, size_t ws_size,
                              hipStream_t stream) {
  const float* x = (const float*)d_in[0];
  const float* pos = (const float*)d_in[1];
  const float* w_attn = (const float*)d_in[2];
  const float* w_proj = (const float*)d_in[3];
  float* out = (float*)d_out;

  char* ws = (char*)d_ws;
  size_t off = 0;
  auto alloc = [&](size_t bytes) {
    void* p = ws + off;
    off = (off + bytes + 255) & ~(size_t)255;
    return p;
  };
  __bf16* xb  = (__bf16*)alloc(2048ull * 2048 * 2);
  __bf16* waT = (__bf16*)alloc(6144ull * 2048 * 2);
  __bf16* wpT = (__bf16*)alloc(2048ull * 2048 * 2);
  __bf16* Qb  = (__bf16*)alloc(2ull * 64 * 1024 * 32 * 2);
  __bf16* Kb  = (__bf16*)alloc(2ull * 64 * 1024 * 32 * 2);
  __bf16* Vtb = (__bf16*)alloc(2ull * 64 * 32 * 1024 * 2);
  __bf16* att = (__bf16*)alloc(2048ull * 2048 * 2);
  float* cosT = (float*)alloc(1024ull * 32 * 4);
  float* sinT = (float*)alloc(1024ull * 32 * 4);

  k_cvt_bf16<<<2048, 256, 0, stream>>>(x, xb, 2048 * 2048);
  k_transpose_bf16<<<dim3(6144 / 64, 2048 / 64), 256, 0, stream>>>(w_attn, waT, 2048, 6144);
  k_transpose_bf16<<<dim3(2048 / 64, 2048 / 64), 256, 0, stream>>>(w_proj, wpT, 2048, 2048);
  k_sincos<<<128, 256, 0, stream>>>(pos, cosT, sinT);

  // qkv = xb @ waT^T with fused RoPE + layout (256x192, 1/CU, unpinned scheduler)
  k_gemmqkv<<<dim3(6144 / 192, 2048 / 256), 512, 0, stream>>>(
      xb, waT, 2048, 6144, 2048, Qb, Kb, Vtb, cosT, sinT);

  k_attn<<<dim3(8, 128), 256, 0, stream>>>(Qb, Kb, Vtb, att);

  // out = att @ wpT^T (2-phase 128^2 dbuf, sched_barriers removed)
  k_gemm<128, 128, 2, 2><<<dim3(2048 / 128, 2048 / 128), 256, 0, stream>>>(
      att, wpT, 2048, 2048, 2048, out);
}

// Round 11
// 166.211 us; speedup vs baseline: 1.1482x; 1.0344x over previous
//
#include <hip/hip_runtime.h>
#include <hip/hip_bf16.h>
#include <math.h>

typedef __attribute__((ext_vector_type(8))) __bf16 bf16x8;
typedef __attribute__((ext_vector_type(4))) __bf16 bf16x4;
typedef __attribute__((ext_vector_type(4))) float f32x4;

#define DEVINL static __device__ __forceinline__

static constexpr int Tlen = 1024;
static constexpr int HD = 32;

DEVINL void gload_lds16(const void* g, void* l) {
  __builtin_amdgcn_global_load_lds(
      (const __attribute__((address_space(1))) void*)g,
      (__attribute__((address_space(3))) void*)l, 16, 0, 0);
}

DEVINL unsigned short bfbits(float x) {
  __bf16 b = (__bf16)x;
  return __builtin_bit_cast(unsigned short, b);
}

// ---------- fused staging kernel: cvt | transpose(w_attn) | transpose(w_proj) | sincos ----
// All four sections are independent; fusing removes 3 inter-kernel bubbles.
__global__ void k_stage(const float* __restrict__ x, __bf16* __restrict__ xb,
                        const float* __restrict__ w_attn, __bf16* __restrict__ waT,
                        const float* __restrict__ w_proj, __bf16* __restrict__ wpT,
                        const float* __restrict__ pos, float* __restrict__ cosT,
                        float* __restrict__ sinT) {
  const int bid = blockIdx.x;
  if (bid < 2048) {
    // section 0: x fp32 -> bf16, 8 elem/thread
    int i = (bid * 256 + threadIdx.x) * 8;
    const float4* p = (const float4*)(x + i);
    float4 a = p[0], b = p[1];
    bf16x8 v;
    v[0] = (__bf16)a.x; v[1] = (__bf16)a.y; v[2] = (__bf16)a.z; v[3] = (__bf16)a.w;
    v[4] = (__bf16)b.x; v[5] = (__bf16)b.y; v[6] = (__bf16)b.z; v[7] = (__bf16)b.w;
    *(bf16x8*)(xb + i) = v;
    return;
  }
  if (bid >= 6144) {
    // section 3: sincos table (128 blocks)
    int idx = (bid - 6144) * 256 + threadIdx.x;  // T*32
    int t = idx >> 5, d = idx & 31;
    float invf = powf(10000.0f, -(float)d * (1.0f / 32.0f));
    float ang = pos[t] * invf;
    cosT[idx] = cosf(ang);
    sinT[idx] = sinf(ang);
    return;
  }
  // sections 1,2: 64x64 transpose fp32->bf16
  const float* w;
  __bf16* wt;
  int n0, k0, K, N;
  if (bid < 5120) {  // w_attn: 3072 blocks, 96 x 32 tiles
    int t = bid - 2048;
    w = w_attn; wt = waT; K = 2048; N = 6144;
    n0 = (t % 96) * 64; k0 = (t / 96) * 64;
  } else {           // w_proj: 1024 blocks, 32 x 32 tiles
    int t = bid - 5120;
    w = w_proj; wt = wpT; K = 2048; N = 2048;
    n0 = (t % 32) * 64; k0 = (t / 32) * 64;
  }
  __shared__ float tile[64][65];
  const int tx = threadIdx.x & 15;
  const int ty = threadIdx.x >> 4;
#pragma unroll
  for (int i = 0; i < 4; ++i) {
    float4 v = *(const float4*)&w[(size_t)(k0 + ty + i * 16) * N + n0 + tx * 4];
    tile[ty + i * 16][tx * 4 + 0] = v.x;
    tile[ty + i * 16][tx * 4 + 1] = v.y;
    tile[ty + i * 16][tx * 4 + 2] = v.z;
    tile[ty + i * 16][tx * 4 + 3] = v.w;
  }
  __syncthreads();
#pragma unroll
  for (int i = 0; i < 4; ++i) {
    int n = ty + i * 16;
    bf16x4 s;
#pragma unroll
    for (int j = 0; j < 4; ++j) s[j] = (__bf16)tile[tx * 4 + j][n];
    *(bf16x4*)&wt[(size_t)(n0 + n) * K + k0 + tx * 4] = s;
  }
}

// ---------- 256x192 GEMM for qkv: 256 blocks = 1/CU, by-clustered XCD swizzle ----
// R10 schedule (unpinned, 2 barriers + 1 vmcnt per K-tile) + R11 change:
// XCD x owns by == x (bid & 7): per-XCD A-panel = 1 MB -> L2-RESIDENT,
// fetched once; only B streams from L3. (R10's bx-clustering gave each XCD
// an 8 MB A working set > 4 MB L2 -> A streamed every K-pass.)
// vmcnt ledger: at CD(kt) end outstanding = A1[kt+1](2) + A0/B[kt+2](5) = 7;
// newest 5 = A0/B[kt+2] -> vmcnt(5) drains ALL of tile kt+1. Tail:
// kt=NT-2 -> vmcnt(0); kt=NT-1 -> no waits.
__launch_bounds__(512, 2)
__global__ void k_gemmqkv(const __bf16* __restrict__ A, const __bf16* __restrict__ Bt,
                          int M, int N, int K,
                          __bf16* __restrict__ Qo, __bf16* __restrict__ Ko,
                          __bf16* __restrict__ Vto, const float* __restrict__ cosT,
                          const float* __restrict__ sinT) {
  constexpr int BM = 256, BN = 192;
  __shared__ alignas(16) __bf16 As[2][BM * 64];
  __shared__ alignas(16) __bf16 Bs[2][BN * 64];

  const int tid = threadIdx.x;
  const int lane = tid & 63;
  const int wave = tid >> 6;            // 0..7
  const int wr = wave >> 2, wc = wave & 3;
  const int l15 = lane & 15;
  const int g = lane >> 4;              // 0..3

  // by-clustered XCD swizzle: bid%8 = XCD = by row; A-panel L2-resident per XCD
  const int bid = blockIdx.y * gridDim.x + blockIdx.x;  // [0,256)
  const int by = bid & 7;               // [0,8) == XCD
  const int bx = bid >> 3;              // [0,32)
  const int m0 = by * BM, n0 = bx * BN;

  f32x4 acc[8][3] = {};

  const int srcChunkElem = ((lane & 7) ^ (lane >> 3)) * 8;
  const int laneRow = lane >> 3;        // 0..7
  const int NT = K >> 6;

  auto stageA = [&](int buf, int kt, int mh) {
    const int k0 = kt << 6;
#pragma unroll
    for (int i = 0; i < 2; ++i) {
      int gi = i * 8 + wave;                                // 0..15
      int rowstart = ((gi >> 3) << 7) + (mh << 6) + ((gi & 7) << 3);
      gload_lds16(A + (size_t)(m0 + rowstart + laneRow) * K + k0 + srcChunkElem,
                  &As[buf][rowstart * 64]);
    }
  };
  auto stageB = [&](int buf, int kt) {
    const int k0 = kt << 6;
#pragma unroll
    for (int i = 0; i < 3; ++i) {
      int rowstart = i * 64 + wave * 8;
      gload_lds16(Bt + (size_t)(n0 + rowstart + laneRow) * K + k0 + srcChunkElem,
                  &Bs[buf][rowstart * 64]);
    }
  };

  // prologue: tile0 complete (7), tile1 A0+B (5); vmcnt(5) -> tile0 resident
  stageA(0, 0, 0); stageB(0, 0); stageA(0, 0, 1);
  if (NT > 1) {
    stageA(1, 1, 0); stageB(1, 1);
    asm volatile("s_waitcnt vmcnt(5)" ::: "memory");
  } else {
    asm volatile("s_waitcnt vmcnt(0)" ::: "memory");
  }
  __builtin_amdgcn_s_barrier();

  bf16x8 af[4][2], af2[4][2], bfv[3][2];

  for (int kt = 0; kt < NT; ++kt) {
    const int cur = kt & 1;
    const char* ab = (const char*)&As[cur][0];
    const char* bb = (const char*)&Bs[cur][0];

    // tile kt fully resident: read AB and CD register sets up front;
    // compiler schedules fine-grained lgkmcnt so af2 reads overlap MFMA-AB.
#pragma unroll
    for (int m = 0; m < 4; ++m)
#pragma unroll
      for (int hh = 0; hh < 2; ++hh) {
        int ar = wr * 128 + m * 16 + l15;
        int chunk = (4 * hh + g) ^ (lane & 7);
        af[m][hh] = *(const bf16x8*)(ab + ar * 128 + chunk * 16);
      }
#pragma unroll
    for (int n = 0; n < 3; ++n)
#pragma unroll
      for (int hh = 0; hh < 2; ++hh) {
        int br = wc * 48 + n * 16 + l15;
        int chunk = (4 * hh + g) ^ (lane & 7);
        bfv[n][hh] = *(const bf16x8*)(bb + br * 128 + chunk * 16);
      }
#pragma unroll
    for (int m = 0; m < 4; ++m)
#pragma unroll
      for (int hh = 0; hh < 2; ++hh) {
        int ar = wr * 128 + 64 + m * 16 + l15;
        int chunk = (4 * hh + g) ^ (lane & 7);
        af2[m][hh] = *(const bf16x8*)(ab + ar * 128 + chunk * 16);
      }
    if (kt + 1 < NT) stageA(cur ^ 1, kt + 1, 1);   // A1[kt+1] (2 gloads)

    __builtin_amdgcn_s_setprio(1);
#pragma unroll
    for (int hh = 0; hh < 2; ++hh)
#pragma unroll
      for (int m = 0; m < 4; ++m)
#pragma unroll
        for (int n = 0; n < 3; ++n)
          acc[m][n] = __builtin_amdgcn_mfma_f32_16x16x32_bf16(af[m][hh], bfv[n][hh], acc[m][n], 0, 0, 0);
    __builtin_amdgcn_s_setprio(0);

    // mid-barrier: all waves' reads of A_mh0/B[cur] issued -> safe to overwrite
    __builtin_amdgcn_s_barrier();
    if (kt + 2 < NT) {  // A0[kt+2],B[kt+2] (5 gloads) into buf cur
      stageA(cur, kt + 2, 0); stageB(cur, kt + 2);
    }

    __builtin_amdgcn_s_setprio(1);
#pragma unroll
    for (int hh = 0; hh < 2; ++hh)
#pragma unroll
      for (int m = 0; m < 4; ++m)
#pragma unroll
        for (int n = 0; n < 3; ++n)
          acc[m + 4][n] = __builtin_amdgcn_mfma_f32_16x16x32_bf16(af2[m][hh], bfv[n][hh], acc[m + 4][n], 0, 0, 0);
    __builtin_amdgcn_s_setprio(0);

    if (kt + 2 < NT) {
      asm volatile("s_waitcnt vmcnt(5)" ::: "memory");   // tile kt+1 fully resident
    } else if (kt + 1 < NT) {
      asm volatile("s_waitcnt vmcnt(0)" ::: "memory");
    }
    if (kt + 1 < NT) __builtin_amdgcn_s_barrier();
  }

  // epilogue: RoPE + layout
#pragma unroll
  for (int m = 0; m < 8; ++m) {
    int row_l = wr * 128 + m * 16 + (g << 2);
#pragma unroll
    for (int n = 0; n < 3; ++n) {
      int col = n0 + wc * 48 + n * 16 + l15;
#pragma unroll
      for (int r = 0; r < 4; ++r) {
        int row = m0 + row_l + r;
        float v = acc[m][n][r];
        int b = row >> 10, t = row & 1023;
        int sec = col >> 11;           // 0=q,1=k,2=v (per-lane; may split mid-tile)
        int c2 = col & 2047;
        int h = c2 >> 5, d = c2 & 31;
        float partner = __shfl_xor(v, 1);  // unconditional, before divergence
        if (sec < 2) {
          float rot = (d & 1) ? partner : -partner;
          float cs = cosT[t * 32 + d], sn = sinT[t * 32 + d];
          float o = v * cs + rot * sn;
          if (sec == 0) o *= 0.17677669529663687f;  // fold 1/sqrt(hd) into Q
          __bf16* dst = sec ? Ko : Qo;
          dst[((size_t)((b << 6) | h) * Tlen + t) * HD + d] = (__bf16)o;
        } else {
          Vto[((size_t)((b << 6) | h) * HD + d) * Tlen + t] = (__bf16)v;
        }
      }
    }
  }
}

// ---------- 2-phase 128x128 GEMM (projection) ----------
template <int BM, int BN, int WM, int WN>
__launch_bounds__(WM * WN * 64)
__global__ void k_gemm(const __bf16* __restrict__ A, const __bf16* __restrict__ Bt,
                       int M, int N, int K, float* __restrict__ Cout) {
  constexpr int T = WM * WN * 64;
  constexpr int M_rep = BM / (WM * 16);
  constexpr int N_rep = BN / (WN * 16);
  constexpr int nA = (BM * 128) / (T * 16);
  constexpr int nB = (BN * 128) / (T * 16);
  constexpr int ROWS_PER_ISSUE = T / 8;

  __shared__ alignas(16) __bf16 As[2][BM * 64];
  __shared__ alignas(16) __bf16 Bs[2][BN * 64];

  const int tid = threadIdx.x;
  const int lane = tid & 63;
  const int wave = tid >> 6;
  const int wr = wave / WN, wc = wave % WN;
  const int l15 = lane & 15;

  const int nwg = gridDim.x * gridDim.y;
  const int bid = blockIdx.y * gridDim.x + blockIdx.x;
  const int cpx = nwg >> 3;
  const int tswz = (bid & 7) * cpx + (bid >> 3);
  const int bx = tswz % gridDim.x, by = tswz / gridDim.x;
  const int m0 = by * BM, n0 = bx * BN;

  f32x4 acc[M_rep][N_rep] = {};

  const int srcChunkElem = ((lane & 7) ^ (lane >> 3)) * 8;
  const int rowInWave = wave * 8 + (lane >> 3);

  const int NT = K >> 6;

  auto stage = [&](int buf, int kt) {
    const int k0 = kt << 6;
#pragma unroll
    for (int i = 0; i < nA; ++i) {
      int row = i * ROWS_PER_ISSUE + rowInWave;
      gload_lds16(A + (size_t)(m0 + row) * K + k0 + srcChunkElem,
                  &As[buf][(i * T + wave * 64) * 8]);
    }
#pragma unroll
    for (int i = 0; i < nB; ++i) {
      int row = i * ROWS_PER_ISSUE + rowInWave;
      gload_lds16(Bt + (size_t)(n0 + row) * K + k0 + srcChunkElem,
                  &Bs[buf][(i * T + wave * 64) * 8]);
    }
  };

  stage(0, 0);

  for (int kt = 0; kt < NT; ++kt) {
    const int cur = kt & 1;
    if (kt + 1 < NT) {
      stage(cur ^ 1, kt + 1);
      asm volatile("s_waitcnt vmcnt(8)" ::: "memory");
    } else {
      asm volatile("s_waitcnt vmcnt(0)" ::: "memory");
    }
    __builtin_amdgcn_s_barrier();

    const char* ab = (const char*)&As[cur][0];
    const char* bb = (const char*)&Bs[cur][0];
#pragma unroll
    for (int hh = 0; hh < 2; ++hh) {
      bf16x8 af[M_rep], bfv[N_rep];
#pragma unroll
      for (int m = 0; m < M_rep; ++m) {
        int ar = wr * (M_rep * 16) + m * 16 + l15;
        int chunk = ((4 * hh + (lane >> 4)) ^ (lane & 7));
        af[m] = *(const bf16x8*)(ab + ar * 128 + chunk * 16);
      }
#pragma unroll
      for (int n = 0; n < N_rep; ++n) {
        int br = wc * (N_rep * 16) + n * 16 + l15;
        int chunk = ((4 * hh + (lane >> 4)) ^ (lane & 7));
        bfv[n] = *(const bf16x8*)(bb + br * 128 + chunk * 16);
      }
      __builtin_amdgcn_s_setprio(1);
#pragma unroll
      for (int m = 0; m < M_rep; ++m)
#pragma unroll
        for (int n = 0; n < N_rep; ++n)
          acc[m][n] = __builtin_amdgcn_mfma_f32_16x16x32_bf16(af[m], bfv[n], acc[m][n], 0, 0, 0);
      __builtin_amdgcn_s_setprio(0);
    }
    __builtin_amdgcn_s_barrier();
  }

#pragma unroll
  for (int m = 0; m < M_rep; ++m) {
    int row_l = wr * (M_rep * 16) + m * 16 + ((lane >> 4) << 2);
#pragma unroll
    for (int n = 0; n < N_rep; ++n) {
      int col = n0 + wc * (N_rep * 16) + n * 16 + l15;
#pragma unroll
      for (int r = 0; r < 4; ++r) {
        int row = m0 + row_l + r;
        Cout[(size_t)row * N + col] = acc[m][n][r];
      }
    }
  }
}

// ---------- flash attention: swapped QK^T, KVBLK=64, static softmax ----------
__launch_bounds__(256)
__global__ void k_attn(const __bf16* __restrict__ Q, const __bf16* __restrict__ Kmat,
                       const __bf16* __restrict__ Vt, __bf16* __restrict__ att) {
  __shared__ alignas(16) __bf16 P[4][32 * 72];
  const int tid = threadIdx.x;
  const int lane = tid & 63;
  const int w = tid >> 6;

  const int orig = blockIdx.y * gridDim.x + blockIdx.x;  // [0,1024)
  const int idx = orig >> 3;                             // [0,128)
  const int bh = (orig & 7) * 16 + (idx >> 3);           // 16 heads per XCD
  const int j = idx & 7;                                 // [0,8)

  const int qt = (w == 0) ? 2 * j : (w == 1) ? 2 * j + 1 : (w == 2) ? 30 - 2 * j : 31 - 2 * j;
  const int q0 = qt * 32;

  const __bf16* Qb = Q + (size_t)bh * Tlen * HD;
  const __bf16* Kb = Kmat + (size_t)bh * Tlen * HD;
  const __bf16* Vb = Vt + (size_t)bh * HD * Tlen;
  __bf16* Pw = &P[w][0];

  const int l15 = lane & 15;
  const int g = lane >> 4;
  const int lk8 = g * 8;

  bf16x8 qf[2];
#pragma unroll
  for (int m = 0; m < 2; ++m)
    qf[m] = *(const bf16x8*)(Qb + (size_t)(q0 + m * 16 + l15) * HD + lk8);

  f32x4 o[2][2] = {};
  float lsum[2] = {0.f, 0.f};

  const int nfull = q0 >> 6;

  for (int kt = 0; kt <= nfull; ++kt) {
    const int k0 = kt * 64;
    bf16x8 kf[4];
#pragma unroll
    for (int n = 0; n < 4; ++n)
      kf[n] = *(const bf16x8*)(Kb + (size_t)(k0 + n * 16 + l15) * HD + lk8);

    f32x4 st[4][2] = {};
#pragma unroll
    for (int n = 0; n < 4; ++n)
#pragma unroll
      for (int m = 0; m < 2; ++m)
        st[n][m] = __builtin_amdgcn_mfma_f32_16x16x32_bf16(kf[n], qf[m], st[n][m], 0, 0, 0);

    bf16x8 vf[2][2];
#pragma unroll
    for (int nn = 0; nn < 2; ++nn)
#pragma unroll
      for (int c = 0; c < 2; ++c)
        vf[nn][c] = *(const bf16x8*)(Vb + (size_t)(nn * 16 + l15) * Tlen + k0 + c * 32 + lk8);

    if (kt == nfull) {
#pragma unroll
      for (int n = 0; n < 4; ++n)
#pragma unroll
        for (int m = 0; m < 2; ++m)
#pragma unroll
          for (int r = 0; r < 4; ++r) {
            int kk = k0 + n * 16 + 4 * g + r;
            int qq = q0 + m * 16 + l15;
            if (kk > qq) st[n][m][r] = -1e30f;
          }
    }

#pragma unroll
    for (int m = 0; m < 2; ++m) {
      float p[16];
      float ps = 0.f;
#pragma unroll
      for (int n = 0; n < 4; ++n)
#pragma unroll
        for (int r = 0; r < 4; ++r) {
          float pv = __expf(st[n][m][r]);
          p[n * 4 + r] = pv;
          ps += pv;
        }
      ps += __shfl_xor(ps, 16);
      ps += __shfl_xor(ps, 32);
      lsum[m] += ps;

#pragma unroll
      for (int n = 0; n < 4; ++n) {
        unsigned int u0 = ((unsigned int)bfbits(p[n * 4 + 1]) << 16) | bfbits(p[n * 4 + 0]);
        unsigned int u1 = ((unsigned int)bfbits(p[n * 4 + 3]) << 16) | bfbits(p[n * 4 + 2]);
        int base = (m * 16 + l15) * 72 + n * 16 + 4 * g;
        *(unsigned int*)&Pw[base] = u0;
        *(unsigned int*)&Pw[base + 2] = u1;
      }
    }

    bf16x8 pa[2][2];
#pragma unroll
    for (int m = 0; m < 2; ++m)
#pragma unroll
      for (int c = 0; c < 2; ++c)
        pa[m][c] = *(const bf16x8*)&Pw[(m * 16 + l15) * 72 + c * 32 + lk8];

#pragma unroll
    for (int m = 0; m < 2; ++m)
#pragma unroll
      for (int nn = 0; nn < 2; ++nn)
#pragma unroll
        for (int c = 0; c < 2; ++c)
          o[m][nn] = __builtin_amdgcn_mfma_f32_16x16x32_bf16(pa[m][c], vf[nn][c], o[m][nn], 0, 0, 0);
  }

  const int b = bh >> 6;
  const int h = bh & 63;
#pragma unroll
  for (int m = 0; m < 2; ++m) {
#pragma unroll
    for (int r = 0; r < 4; ++r) {
      float ls = __shfl(lsum[m], (lane & 48) + ((lane >> 4) << 2) + r);
      float inv = 1.0f / ls;
      int t = q0 + m * 16 + 4 * g + r;
#pragma unroll
      for (int nn = 0; nn < 2; ++nn) {
        float ov = o[m][nn][r] * inv;
        att[((size_t)(b * Tlen + t)) * 2048 + h * 32 + nn * 16 + l15] = (__bf16)ov;
      }
    }
  }
}

// ---------- launch ----------

extern "C" void kernel_launch(void* const* d_in, const int* in_sizes, int n_in,
                              void* d_out, int out_size, void* d_ws, size_t ws_size,
                              hipStream_t stream) {
  const float* x = (const float*)d_in[0];
  const float* pos = (const float*)d_in[1];
  const float* w_attn = (const float*)d_in[2];
  const float* w_proj = (const float*)d_in[3];
  float* out = (float*)d_out;

  char* ws = (char*)d_ws;
  size_t off = 0;
  auto alloc = [&](size_t bytes) {
    void* p = ws + off;
    off = (off + bytes + 255) & ~(size_t)255;
    return p;
  };
  __bf16* xb  = (__bf16*)alloc(2048ull * 2048 * 2);
  __bf16* waT = (__bf16*)alloc(6144ull * 2048 * 2);
  __bf16* wpT = (__bf16*)alloc(2048ull * 2048 * 2);
  __bf16* Qb  = (__bf16*)alloc(2ull * 64 * 1024 * 32 * 2);
  __bf16* Kb  = (__bf16*)alloc(2ull * 64 * 1024 * 32 * 2);
  __bf16* Vtb = (__bf16*)alloc(2ull * 64 * 32 * 1024 * 2);
  __bf16* att = (__bf16*)alloc(2048ull * 2048 * 2);
  float* cosT = (float*)alloc(1024ull * 32 * 4);
  float* sinT = (float*)alloc(1024ull * 32 * 4);

  // fused staging: cvt (2048) | transpose w_attn (3072) | transpose w_proj (1024) | sincos (128)
  k_stage<<<6272, 256, 0, stream>>>(x, xb, w_attn, waT, w_proj, wpT, pos, cosT, sinT);

  // qkv = xb @ waT^T with fused RoPE + layout (256x192, 1/CU, by-clustered XCD)
  k_gemmqkv<<<dim3(32, 8), 512, 0, stream>>>(
      xb, waT, 2048, 6144, 2048, Qb, Kb, Vtb, cosT, sinT);

  k_attn<<<dim3(8, 128), 256, 0, stream>>>(Qb, Kb, Vtb, att);

  // out = att @ wpT^T (2-phase 128^2 dbuf)
  k_gemm<128, 128, 2, 2><<<dim3(2048 / 128, 2048 / 128), 256, 0, stream>>>(
      att, wpT, 2048, 2048, 2048, out);
}

// Round 12
// 163.802 us; speedup vs baseline: 1.1651x; 1.0147x over previous
//
#include <hip/hip_runtime.h>
#include <hip/hip_bf16.h>
#include <math.h>

typedef __attribute__((ext_vector_type(8))) __bf16 bf16x8;
typedef __attribute__((ext_vector_type(4))) __bf16 bf16x4;
typedef __attribute__((ext_vector_type(4))) float f32x4;

#define DEVINL static __device__ __forceinline__

static constexpr int Tlen = 1024;
static constexpr int HD = 32;

DEVINL void gload_lds16(const void* g, void* l) {
  __builtin_amdgcn_global_load_lds(
      (const __attribute__((address_space(1))) void*)g,
      (__attribute__((address_space(3))) void*)l, 16, 0, 0);
}

DEVINL unsigned short bfbits(float x) {
  __bf16 b = (__bf16)x;
  return __builtin_bit_cast(unsigned short, b);
}

// ---------- fused staging kernel: cvt | transpose(w_attn) | transpose(w_proj) | sincos ----
__global__ void k_stage(const float* __restrict__ x, __bf16* __restrict__ xb,
                        const float* __restrict__ w_attn, __bf16* __restrict__ waT,
                        const float* __restrict__ w_proj, __bf16* __restrict__ wpT,
                        const float* __restrict__ pos, float* __restrict__ cosT,
                        float* __restrict__ sinT) {
  const int bid = blockIdx.x;
  if (bid < 2048) {
    int i = (bid * 256 + threadIdx.x) * 8;
    const float4* p = (const float4*)(x + i);
    float4 a = p[0], b = p[1];
    bf16x8 v;
    v[0] = (__bf16)a.x; v[1] = (__bf16)a.y; v[2] = (__bf16)a.z; v[3] = (__bf16)a.w;
    v[4] = (__bf16)b.x; v[5] = (__bf16)b.y; v[6] = (__bf16)b.z; v[7] = (__bf16)b.w;
    *(bf16x8*)(xb + i) = v;
    return;
  }
  if (bid >= 6144) {
    int idx = (bid - 6144) * 256 + threadIdx.x;  // T*32
    int t = idx >> 5, d = idx & 31;
    float invf = powf(10000.0f, -(float)d * (1.0f / 32.0f));
    float ang = pos[t] * invf;
    cosT[idx] = cosf(ang);
    sinT[idx] = sinf(ang);
    return;
  }
  const float* w;
  __bf16* wt;
  int n0, k0, K, N;
  if (bid < 5120) {  // w_attn: 3072 blocks
    int t = bid - 2048;
    w = w_attn; wt = waT; K = 2048; N = 6144;
    n0 = (t % 96) * 64; k0 = (t / 96) * 64;
  } else {           // w_proj: 1024 blocks
    int t = bid - 5120;
    w = w_proj; wt = wpT; K = 2048; N = 2048;
    n0 = (t % 32) * 64; k0 = (t / 32) * 64;
  }
  __shared__ float tile[64][65];
  const int tx = threadIdx.x & 15;
  const int ty = threadIdx.x >> 4;
#pragma unroll
  for (int i = 0; i < 4; ++i) {
    float4 v = *(const float4*)&w[(size_t)(k0 + ty + i * 16) * N + n0 + tx * 4];
    tile[ty + i * 16][tx * 4 + 0] = v.x;
    tile[ty + i * 16][tx * 4 + 1] = v.y;
    tile[ty + i * 16][tx * 4 + 2] = v.z;
    tile[ty + i * 16][tx * 4 + 3] = v.w;
  }
  __syncthreads();
#pragma unroll
  for (int i = 0; i < 4; ++i) {
    int n = ty + i * 16;
    bf16x4 s;
#pragma unroll
    for (int j = 0; j < 4; ++j) s[j] = (__bf16)tile[tx * 4 + j][n];
    *(bf16x4*)&wt[(size_t)(n0 + n) * K + k0 + tx * 4] = s;
  }
}

// ---------- 128x192 GEMM for qkv: 512 blocks = 2/CU (80 KiB LDS each) ----------
// SAME per-wave fragment program and schedule as R11 (which ran 256x192, 8
// waves, 1 block/CU): 4 waves, each computes 128x48, M_rep=8, N_rep=3.
// Experiment: two independent barrier domains per CU -> inter-block wave
// overlap hides the vmcnt/barrier drains (m114 mechanism).
// Staging: 10 issues/thread/K-tile (A0:2, B:6, A1:2).
// vmcnt ledger: after kt-1's vmcnt(8): <=8 outstanding (A0/B[kt+1]).
// kt issues A1[kt+1](2) early, A0/B[kt+2](8) late -> <=18; at kt end need
// tile kt+1 drained; 8 newest = A0/B[kt+2] -> vmcnt(8). Tail: kt=NT-2 ->
// vmcnt(0); kt=NT-1 -> none.
// by-clustered XCD swizzle: XCD x owns by in {2x,2x+1} -> A-panel 1 MB
// L2-resident per XCD; only B streams.
__launch_bounds__(256, 2)
__global__ void k_gemmqkv(const __bf16* __restrict__ A, const __bf16* __restrict__ Bt,
                          int M, int N, int K,
                          __bf16* __restrict__ Qo, __bf16* __restrict__ Ko,
                          __bf16* __restrict__ Vto, const float* __restrict__ cosT,
                          const float* __restrict__ sinT) {
  constexpr int BM = 128, BN = 192;
  __shared__ alignas(16) __bf16 As[2][BM * 64];   // 32 KiB
  __shared__ alignas(16) __bf16 Bs[2][BN * 64];   // 48 KiB

  const int tid = threadIdx.x;
  const int lane = tid & 63;
  const int wave = tid >> 6;            // 0..3
  const int wc = wave;                  // 4 N-columns of 48
  const int l15 = lane & 15;
  const int g = lane >> 4;              // 0..3

  // by-clustered XCD swizzle over 512 blocks
  const int bid = blockIdx.x;           // [0,512)
  const int x = bid & 7;                // XCD
  const int u = bid >> 3;               // [0,64)
  const int by = 2 * x + (u & 1);       // [0,16)
  const int bx = u >> 1;                // [0,32)
  const int m0 = by * BM, n0 = bx * BN;

  f32x4 acc[8][3] = {};

  const int srcChunkElem = ((lane & 7) ^ (lane >> 3)) * 8;
  const int laneRow = lane >> 3;        // 0..7
  const int NT = K >> 6;

  // A half mh: rows [mh*64, mh*64+64); 2 issues x 32 rows
  auto stageA = [&](int buf, int kt, int mh) {
    const int k0 = kt << 6;
#pragma unroll
    for (int i = 0; i < 2; ++i) {
      int rowstart = mh * 64 + i * 32 + wave * 8;
      gload_lds16(A + (size_t)(m0 + rowstart + laneRow) * K + k0 + srcChunkElem,
                  &As[buf][rowstart * 64]);
    }
  };
  // B whole tile: 192 rows = 6 issues x 32 rows
  auto stageB = [&](int buf, int kt) {
    const int k0 = kt << 6;
#pragma unroll
    for (int i = 0; i < 6; ++i) {
      int rowstart = i * 32 + wave * 8;
      gload_lds16(Bt + (size_t)(n0 + rowstart + laneRow) * K + k0 + srcChunkElem,
                  &Bs[buf][rowstart * 64]);
    }
  };

  // prologue: tile0 complete (10), tile1 A0+B (8); vmcnt(8) -> tile0 resident
  stageA(0, 0, 0); stageB(0, 0); stageA(0, 0, 1);
  if (NT > 1) {
    stageA(1, 1, 0); stageB(1, 1);
    asm volatile("s_waitcnt vmcnt(8)" ::: "memory");
  } else {
    asm volatile("s_waitcnt vmcnt(0)" ::: "memory");
  }
  __builtin_amdgcn_s_barrier();

  bf16x8 af[4][2], af2[4][2], bfv[3][2];

  for (int kt = 0; kt < NT; ++kt) {
    const int cur = kt & 1;
    const char* ab = (const char*)&As[cur][0];
    const char* bb = (const char*)&Bs[cur][0];

    // tile kt fully resident: read all register sets up front
#pragma unroll
    for (int m = 0; m < 4; ++m)
#pragma unroll
      for (int hh = 0; hh < 2; ++hh) {
        int ar = m * 16 + l15;
        int chunk = (4 * hh + g) ^ (lane & 7);
        af[m][hh] = *(const bf16x8*)(ab + ar * 128 + chunk * 16);
      }
#pragma unroll
    for (int n = 0; n < 3; ++n)
#pragma unroll
      for (int hh = 0; hh < 2; ++hh) {
        int br = wc * 48 + n * 16 + l15;
        int chunk = (4 * hh + g) ^ (lane & 7);
        bfv[n][hh] = *(const bf16x8*)(bb + br * 128 + chunk * 16);
      }
#pragma unroll
    for (int m = 0; m < 4; ++m)
#pragma unroll
      for (int hh = 0; hh < 2; ++hh) {
        int ar = 64 + m * 16 + l15;
        int chunk = (4 * hh + g) ^ (lane & 7);
        af2[m][hh] = *(const bf16x8*)(ab + ar * 128 + chunk * 16);
      }
    if (kt + 1 < NT) stageA(cur ^ 1, kt + 1, 1);   // A1[kt+1] (2 gloads)

    __builtin_amdgcn_s_setprio(1);
#pragma unroll
    for (int hh = 0; hh < 2; ++hh)
#pragma unroll
      for (int m = 0; m < 4; ++m)
#pragma unroll
        for (int n = 0; n < 3; ++n)
          acc[m][n] = __builtin_amdgcn_mfma_f32_16x16x32_bf16(af[m][hh], bfv[n][hh], acc[m][n], 0, 0, 0);
    __builtin_amdgcn_s_setprio(0);

    // mid-barrier: all waves' reads of buf[cur] issued -> safe to overwrite
    __builtin_amdgcn_s_barrier();
    if (kt + 2 < NT) {  // A0[kt+2],B[kt+2] (8 gloads) into buf cur
      stageA(cur, kt + 2, 0); stageB(cur, kt + 2);
    }

    __builtin_amdgcn_s_setprio(1);
#pragma unroll
    for (int hh = 0; hh < 2; ++hh)
#pragma unroll
      for (int m = 0; m < 4; ++m)
#pragma unroll
        for (int n = 0; n < 3; ++n)
          acc[m + 4][n] = __builtin_amdgcn_mfma_f32_16x16x32_bf16(af2[m][hh], bfv[n][hh], acc[m + 4][n], 0, 0, 0);
    __builtin_amdgcn_s_setprio(0);

    if (kt + 2 < NT) {
      asm volatile("s_waitcnt vmcnt(8)" ::: "memory");   // tile kt+1 fully resident
    } else if (kt + 1 < NT) {
      asm volatile("s_waitcnt vmcnt(0)" ::: "memory");
    }
    if (kt + 1 < NT) __builtin_amdgcn_s_barrier();
  }

  // epilogue: RoPE + layout
#pragma unroll
  for (int m = 0; m < 8; ++m) {
    int row_l = m * 16 + (g << 2);
#pragma unroll
    for (int n = 0; n < 3; ++n) {
      int col = n0 + wc * 48 + n * 16 + l15;
#pragma unroll
      for (int r = 0; r < 4; ++r) {
        int row = m0 + row_l + r;
        float v = acc[m][n][r];
        int b = row >> 10, t = row & 1023;
        int sec = col >> 11;           // 0=q,1=k,2=v (per-lane; may split mid-tile)
        int c2 = col & 2047;
        int h = c2 >> 5, d = c2 & 31;
        float partner = __shfl_xor(v, 1);  // unconditional, before divergence
        if (sec < 2) {
          float rot = (d & 1) ? partner : -partner;
          float cs = cosT[t * 32 + d], sn = sinT[t * 32 + d];
          float o = v * cs + rot * sn;
          if (sec == 0) o *= 0.17677669529663687f;  // fold 1/sqrt(hd) into Q
          __bf16* dst = sec ? Ko : Qo;
          dst[((size_t)((b << 6) | h) * Tlen + t) * HD + d] = (__bf16)o;
        } else {
          Vto[((size_t)((b << 6) | h) * HD + d) * Tlen + t] = (__bf16)v;
        }
      }
    }
  }
}

// ---------- 2-phase 128x128 GEMM (projection) ----------
template <int BM, int BN, int WM, int WN>
__launch_bounds__(WM * WN * 64)
__global__ void k_gemm(const __bf16* __restrict__ A, const __bf16* __restrict__ Bt,
                       int M, int N, int K, float* __restrict__ Cout) {
  constexpr int T = WM * WN * 64;
  constexpr int M_rep = BM / (WM * 16);
  constexpr int N_rep = BN / (WN * 16);
  constexpr int nA = (BM * 128) / (T * 16);
  constexpr int nB = (BN * 128) / (T * 16);
  constexpr int ROWS_PER_ISSUE = T / 8;

  __shared__ alignas(16) __bf16 As[2][BM * 64];
  __shared__ alignas(16) __bf16 Bs[2][BN * 64];

  const int tid = threadIdx.x;
  const int lane = tid & 63;
  const int wave = tid >> 6;
  const int wr = wave / WN, wc = wave % WN;
  const int l15 = lane & 15;

  const int nwg = gridDim.x * gridDim.y;
  const int bid = blockIdx.y * gridDim.x + blockIdx.x;
  const int cpx = nwg >> 3;
  const int tswz = (bid & 7) * cpx + (bid >> 3);
  const int bx = tswz % gridDim.x, by = tswz / gridDim.x;
  const int m0 = by * BM, n0 = bx * BN;

  f32x4 acc[M_rep][N_rep] = {};

  const int srcChunkElem = ((lane & 7) ^ (lane >> 3)) * 8;
  const int rowInWave = wave * 8 + (lane >> 3);

  const int NT = K >> 6;

  auto stage = [&](int buf, int kt) {
    const int k0 = kt << 6;
#pragma unroll
    for (int i = 0; i < nA; ++i) {
      int row = i * ROWS_PER_ISSUE + rowInWave;
      gload_lds16(A + (size_t)(m0 + row) * K + k0 + srcChunkElem,
                  &As[buf][(i * T + wave * 64) * 8]);
    }
#pragma unroll
    for (int i = 0; i < nB; ++i) {
      int row = i * ROWS_PER_ISSUE + rowInWave;
      gload_lds16(Bt + (size_t)(n0 + row) * K + k0 + srcChunkElem,
                  &Bs[buf][(i * T + wave * 64) * 8]);
    }
  };

  stage(0, 0);

  for (int kt = 0; kt < NT; ++kt) {
    const int cur = kt & 1;
    if (kt + 1 < NT) {
      stage(cur ^ 1, kt + 1);
      asm volatile("s_waitcnt vmcnt(8)" ::: "memory");
    } else {
      asm volatile("s_waitcnt vmcnt(0)" ::: "memory");
    }
    __builtin_amdgcn_s_barrier();

    const char* ab = (const char*)&As[cur][0];
    const char* bb = (const char*)&Bs[cur][0];
#pragma unroll
    for (int hh = 0; hh < 2; ++hh) {
      bf16x8 af[M_rep], bfv[N_rep];
#pragma unroll
      for (int m = 0; m < M_rep; ++m) {
        int ar = wr * (M_rep * 16) + m * 16 + l15;
        int chunk = ((4 * hh + (lane >> 4)) ^ (lane & 7));
        af[m] = *(const bf16x8*)(ab + ar * 128 + chunk * 16);
      }
#pragma unroll
      for (int n = 0; n < N_rep; ++n) {
        int br = wc * (N_rep * 16) + n * 16 + l15;
        int chunk = ((4 * hh + (lane >> 4)) ^ (lane & 7));
        bfv[n] = *(const bf16x8*)(bb + br * 128 + chunk * 16);
      }
      __builtin_amdgcn_s_setprio(1);
#pragma unroll
      for (int m = 0; m < M_rep; ++m)
#pragma unroll
        for (int n = 0; n < N_rep; ++n)
          acc[m][n] = __builtin_amdgcn_mfma_f32_16x16x32_bf16(af[m], bfv[n], acc[m][n], 0, 0, 0);
      __builtin_amdgcn_s_setprio(0);
    }
    __builtin_amdgcn_s_barrier();
  }

#pragma unroll
  for (int m = 0; m < M_rep; ++m) {
    int row_l = wr * (M_rep * 16) + m * 16 + ((lane >> 4) << 2);
#pragma unroll
    for (int n = 0; n < N_rep; ++n) {
      int col = n0 + wc * (N_rep * 16) + n * 16 + l15;
#pragma unroll
      for (int r = 0; r < 4; ++r) {
        int row = m0 + row_l + r;
        Cout[(size_t)row * N + col] = acc[m][n][r];
      }
    }
  }
}

// ---------- flash attention: swapped QK^T, KVBLK=64, static softmax ----------
__launch_bounds__(256)
__global__ void k_attn(const __bf16* __restrict__ Q, const __bf16* __restrict__ Kmat,
                       const __bf16* __restrict__ Vt, __bf16* __restrict__ att) {
  __shared__ alignas(16) __bf16 P[4][32 * 72];
  const int tid = threadIdx.x;
  const int lane = tid & 63;
  const int w = tid >> 6;

  const int orig = blockIdx.y * gridDim.x + blockIdx.x;  // [0,1024)
  const int idx = orig >> 3;                             // [0,128)
  const int bh = (orig & 7) * 16 + (idx >> 3);           // 16 heads per XCD
  const int j = idx & 7;                                 // [0,8)

  const int qt = (w == 0) ? 2 * j : (w == 1) ? 2 * j + 1 : (w == 2) ? 30 - 2 * j : 31 - 2 * j;
  const int q0 = qt * 32;

  const __bf16* Qb = Q + (size_t)bh * Tlen * HD;
  const __bf16* Kb = Kmat + (size_t)bh * Tlen * HD;
  const __bf16* Vb = Vt + (size_t)bh * HD * Tlen;
  __bf16* Pw = &P[w][0];

  const int l15 = lane & 15;
  const int g = lane >> 4;
  const int lk8 = g * 8;

  bf16x8 qf[2];
#pragma unroll
  for (int m = 0; m < 2; ++m)
    qf[m] = *(const bf16x8*)(Qb + (size_t)(q0 + m * 16 + l15) * HD + lk8);

  f32x4 o[2][2] = {};
  float lsum[2] = {0.f, 0.f};

  const int nfull = q0 >> 6;

  for (int kt = 0; kt <= nfull; ++kt) {
    const int k0 = kt * 64;
    bf16x8 kf[4];
#pragma unroll
    for (int n = 0; n < 4; ++n)
      kf[n] = *(const bf16x8*)(Kb + (size_t)(k0 + n * 16 + l15) * HD + lk8);

    f32x4 st[4][2] = {};
#pragma unroll
    for (int n = 0; n < 4; ++n)
#pragma unroll
      for (int m = 0; m < 2; ++m)
        st[n][m] = __builtin_amdgcn_mfma_f32_16x16x32_bf16(kf[n], qf[m], st[n][m], 0, 0, 0);

    bf16x8 vf[2][2];
#pragma unroll
    for (int nn = 0; nn < 2; ++nn)
#pragma unroll
      for (int c = 0; c < 2; ++c)
        vf[nn][c] = *(const bf16x8*)(Vb + (size_t)(nn * 16 + l15) * Tlen + k0 + c * 32 + lk8);

    if (kt == nfull) {
#pragma unroll
      for (int n = 0; n < 4; ++n)
#pragma unroll
        for (int m = 0; m < 2; ++m)
#pragma unroll
          for (int r = 0; r < 4; ++r) {
            int kk = k0 + n * 16 + 4 * g + r;
            int qq = q0 + m * 16 + l15;
            if (kk > qq) st[n][m][r] = -1e30f;
          }
    }

#pragma unroll
    for (int m = 0; m < 2; ++m) {
      float p[16];
      float ps = 0.f;
#pragma unroll
      for (int n = 0; n < 4; ++n)
#pragma unroll
        for (int r = 0; r < 4; ++r) {
          float pv = __expf(st[n][m][r]);
          p[n * 4 + r] = pv;
          ps += pv;
        }
      ps += __shfl_xor(ps, 16);
      ps += __shfl_xor(ps, 32);
      lsum[m] += ps;

#pragma unroll
      for (int n = 0; n < 4; ++n) {
        unsigned int u0 = ((unsigned int)bfbits(p[n * 4 + 1]) << 16) | bfbits(p[n * 4 + 0]);
        unsigned int u1 = ((unsigned int)bfbits(p[n * 4 + 3]) << 16) | bfbits(p[n * 4 + 2]);
        int base = (m * 16 + l15) * 72 + n * 16 + 4 * g;
        *(unsigned int*)&Pw[base] = u0;
        *(unsigned int*)&Pw[base + 2] = u1;
      }
    }

    bf16x8 pa[2][2];
#pragma unroll
    for (int m = 0; m < 2; ++m)
#pragma unroll
      for (int c = 0; c < 2; ++c)
        pa[m][c] = *(const bf16x8*)&Pw[(m * 16 + l15) * 72 + c * 32 + lk8];

#pragma unroll
    for (int m = 0; m < 2; ++m)
#pragma unroll
      for (int nn = 0; nn < 2; ++nn)
#pragma unroll
        for (int c = 0; c < 2; ++c)
          o[m][nn] = __builtin_amdgcn_mfma_f32_16x16x32_bf16(pa[m][c], vf[nn][c], o[m][nn], 0, 0, 0);
  }

  const int b = bh >> 6;
  const int h = bh & 63;
#pragma unroll
  for (int m = 0; m < 2; ++m) {
#pragma unroll
    for (int r = 0; r < 4; ++r) {
      float ls = __shfl(lsum[m], (lane & 48) + ((lane >> 4) << 2) + r);
      float inv = 1.0f / ls;
      int t = q0 + m * 16 + 4 * g + r;
#pragma unroll
      for (int nn = 0; nn < 2; ++nn) {
        float ov = o[m][nn][r] * inv;
        att[((size_t)(b * Tlen + t)) * 2048 + h * 32 + nn * 16 + l15] = (__bf16)ov;
      }
    }
  }
}

// ---------- launch ----------

extern "C" void kernel_launch(void* const* d_in, const int* in_sizes, int n_in,
                              void* d_out, int out_size, void* d_ws, size_t ws_size,
                              hipStream_t stream) {
  const float* x = (const float*)d_in[0];
  const float* pos = (const float*)d_in[1];
  const float* w_attn = (const float*)d_in[2];
  const float* w_proj = (const float*)d_in[3];
  float* out = (float*)d_out;

  char* ws = (char*)d_ws;
  size_t off = 0;
  auto alloc = [&](size_t bytes) {
    void* p = ws + off;
    off = (off + bytes + 255) & ~(size_t)255;
    return p;
  };
  __bf16* xb  = (__bf16*)alloc(2048ull * 2048 * 2);
  __bf16* waT = (__bf16*)alloc(6144ull * 2048 * 2);
  __bf16* wpT = (__bf16*)alloc(2048ull * 2048 * 2);
  __bf16* Qb  = (__bf16*)alloc(2ull * 64 * 1024 * 32 * 2);
  __bf16* Kb  = (__bf16*)alloc(2ull * 64 * 1024 * 32 * 2);
  __bf16* Vtb = (__bf16*)alloc(2ull * 64 * 32 * 1024 * 2);
  __bf16* att = (__bf16*)alloc(2048ull * 2048 * 2);
  float* cosT = (float*)alloc(1024ull * 32 * 4);
  float* sinT = (float*)alloc(1024ull * 32 * 4);

  // fused staging: cvt (2048) | transpose w_attn (3072) | transpose w_proj (1024) | sincos (128)
  k_stage<<<6272, 256, 0, stream>>>(x, xb, w_attn, waT, w_proj, wpT, pos, cosT, sinT);

  // qkv = xb @ waT^T with fused RoPE + layout (128x192, 512 blocks = 2/CU)
  k_gemmqkv<<<512, 256, 0, stream>>>(
      xb, waT, 2048, 6144, 2048, Qb, Kb, Vtb, cosT, sinT);

  k_attn<<<dim3(8, 128), 256, 0, stream>>>(Qb, Kb, Vtb, att);

  // out = att @ wpT^T (2-phase 128^2 dbuf)
  k_gemm<128, 128, 2, 2><<<dim3(2048 / 128, 2048 / 128), 256, 0, stream>>>(
      att, wpT, 2048, 2048, 2048, out);
}

// Round 13
// 157.065 us; speedup vs baseline: 1.2151x; 1.0429x over previous
//
#include <hip/hip_runtime.h>
#include <hip/hip_bf16.h>
#include <math.h>

typedef __attribute__((ext_vector_type(8))) __bf16 bf16x8;
typedef __attribute__((ext_vector_type(4))) __bf16 bf16x4;
typedef __attribute__((ext_vector_type(4))) float f32x4;

#define DEVINL static __device__ __forceinline__

static constexpr int Tlen = 1024;
static constexpr int HD = 32;

DEVINL void gload_lds16(const void* g, void* l) {
  __builtin_amdgcn_global_load_lds(
      (const __attribute__((address_space(1))) void*)g,
      (__attribute__((address_space(3))) void*)l, 16, 0, 0);
}

DEVINL unsigned short bfbits(float x) {
  __bf16 b = (__bf16)x;
  return __builtin_bit_cast(unsigned short, b);
}

// ---------- fused staging kernel: cvt | transpose(w_attn) | transpose(w_proj) | sincos ----
__global__ void k_stage(const float* __restrict__ x, __bf16* __restrict__ xb,
                        const float* __restrict__ w_attn, __bf16* __restrict__ waT,
                        const float* __restrict__ w_proj, __bf16* __restrict__ wpT,
                        const float* __restrict__ pos, float* __restrict__ cosT,
                        float* __restrict__ sinT) {
  const int bid = blockIdx.x;
  if (bid < 2048) {
    int i = (bid * 256 + threadIdx.x) * 8;
    const float4* p = (const float4*)(x + i);
    float4 a = p[0], b = p[1];
    bf16x8 v;
    v[0] = (__bf16)a.x; v[1] = (__bf16)a.y; v[2] = (__bf16)a.z; v[3] = (__bf16)a.w;
    v[4] = (__bf16)b.x; v[5] = (__bf16)b.y; v[6] = (__bf16)b.z; v[7] = (__bf16)b.w;
    *(bf16x8*)(xb + i) = v;
    return;
  }
  if (bid >= 6144) {
    int idx = (bid - 6144) * 256 + threadIdx.x;  // T*32
    int t = idx >> 5, d = idx & 31;
    float invf = powf(10000.0f, -(float)d * (1.0f / 32.0f));
    float ang = pos[t] * invf;
    cosT[idx] = cosf(ang);
    sinT[idx] = sinf(ang);
    return;
  }
  const float* w;
  __bf16* wt;
  int n0, k0, K, N;
  if (bid < 5120) {  // w_attn: 3072 blocks
    int t = bid - 2048;
    w = w_attn; wt = waT; K = 2048; N = 6144;
    n0 = (t % 96) * 64; k0 = (t / 96) * 64;
  } else {           // w_proj: 1024 blocks
    int t = bid - 5120;
    w = w_proj; wt = wpT; K = 2048; N = 2048;
    n0 = (t % 32) * 64; k0 = (t / 32) * 64;
  }
  __shared__ float tile[64][65];
  const int tx = threadIdx.x & 15;
  const int ty = threadIdx.x >> 4;
#pragma unroll
  for (int i = 0; i < 4; ++i) {
    float4 v = *(const float4*)&w[(size_t)(k0 + ty + i * 16) * N + n0 + tx * 4];
    tile[ty + i * 16][tx * 4 + 0] = v.x;
    tile[ty + i * 16][tx * 4 + 1] = v.y;
    tile[ty + i * 16][tx * 4 + 2] = v.z;
    tile[ty + i * 16][tx * 4 + 3] = v.w;
  }
  __syncthreads();
#pragma unroll
  for (int i = 0; i < 4; ++i) {
    int n = ty + i * 16;
    bf16x4 s;
#pragma unroll
    for (int j = 0; j < 4; ++j) s[j] = (__bf16)tile[tx * 4 + j][n];
    *(bf16x4*)&wt[(size_t)(n0 + n) * K + k0 + tx * 4] = s;
  }
}

// ---------- 128x192 GEMM for qkv: 512 blocks = 2/CU (R12-verified, 81.5us) ----------
__launch_bounds__(256, 2)
__global__ void k_gemmqkv(const __bf16* __restrict__ A, const __bf16* __restrict__ Bt,
                          int M, int N, int K,
                          __bf16* __restrict__ Qo, __bf16* __restrict__ Ko,
                          __bf16* __restrict__ Vto, const float* __restrict__ cosT,
                          const float* __restrict__ sinT) {
  constexpr int BM = 128, BN = 192;
  __shared__ alignas(16) __bf16 As[2][BM * 64];   // 32 KiB
  __shared__ alignas(16) __bf16 Bs[2][BN * 64];   // 48 KiB

  const int tid = threadIdx.x;
  const int lane = tid & 63;
  const int wave = tid >> 6;            // 0..3
  const int wc = wave;
  const int l15 = lane & 15;
  const int g = lane >> 4;              // 0..3

  const int bid = blockIdx.x;           // [0,512)
  const int x = bid & 7;                // XCD
  const int u = bid >> 3;               // [0,64)
  const int by = 2 * x + (u & 1);       // [0,16)
  const int bx = u >> 1;                // [0,32)
  const int m0 = by * BM, n0 = bx * BN;

  f32x4 acc[8][3] = {};

  const int srcChunkElem = ((lane & 7) ^ (lane >> 3)) * 8;
  const int laneRow = lane >> 3;        // 0..7
  const int NT = K >> 6;

  auto stageA = [&](int buf, int kt, int mh) {
    const int k0 = kt << 6;
#pragma unroll
    for (int i = 0; i < 2; ++i) {
      int rowstart = mh * 64 + i * 32 + wave * 8;
      gload_lds16(A + (size_t)(m0 + rowstart + laneRow) * K + k0 + srcChunkElem,
                  &As[buf][rowstart * 64]);
    }
  };
  auto stageB = [&](int buf, int kt) {
    const int k0 = kt << 6;
#pragma unroll
    for (int i = 0; i < 6; ++i) {
      int rowstart = i * 32 + wave * 8;
      gload_lds16(Bt + (size_t)(n0 + rowstart + laneRow) * K + k0 + srcChunkElem,
                  &Bs[buf][rowstart * 64]);
    }
  };

  stageA(0, 0, 0); stageB(0, 0); stageA(0, 0, 1);
  if (NT > 1) {
    stageA(1, 1, 0); stageB(1, 1);
    asm volatile("s_waitcnt vmcnt(8)" ::: "memory");
  } else {
    asm volatile("s_waitcnt vmcnt(0)" ::: "memory");
  }
  __builtin_amdgcn_s_barrier();

  bf16x8 af[4][2], af2[4][2], bfv[3][2];

  for (int kt = 0; kt < NT; ++kt) {
    const int cur = kt & 1;
    const char* ab = (const char*)&As[cur][0];
    const char* bb = (const char*)&Bs[cur][0];

#pragma unroll
    for (int m = 0; m < 4; ++m)
#pragma unroll
      for (int hh = 0; hh < 2; ++hh) {
        int ar = m * 16 + l15;
        int chunk = (4 * hh + g) ^ (lane & 7);
        af[m][hh] = *(const bf16x8*)(ab + ar * 128 + chunk * 16);
      }
#pragma unroll
    for (int n = 0; n < 3; ++n)
#pragma unroll
      for (int hh = 0; hh < 2; ++hh) {
        int br = wc * 48 + n * 16 + l15;
        int chunk = (4 * hh + g) ^ (lane & 7);
        bfv[n][hh] = *(const bf16x8*)(bb + br * 128 + chunk * 16);
      }
#pragma unroll
    for (int m = 0; m < 4; ++m)
#pragma unroll
      for (int hh = 0; hh < 2; ++hh) {
        int ar = 64 + m * 16 + l15;
        int chunk = (4 * hh + g) ^ (lane & 7);
        af2[m][hh] = *(const bf16x8*)(ab + ar * 128 + chunk * 16);
      }
    if (kt + 1 < NT) stageA(cur ^ 1, kt + 1, 1);

    __builtin_amdgcn_s_setprio(1);
#pragma unroll
    for (int hh = 0; hh < 2; ++hh)
#pragma unroll
      for (int m = 0; m < 4; ++m)
#pragma unroll
        for (int n = 0; n < 3; ++n)
          acc[m][n] = __builtin_amdgcn_mfma_f32_16x16x32_bf16(af[m][hh], bfv[n][hh], acc[m][n], 0, 0, 0);
    __builtin_amdgcn_s_setprio(0);

    __builtin_amdgcn_s_barrier();
    if (kt + 2 < NT) {
      stageA(cur, kt + 2, 0); stageB(cur, kt + 2);
    }

    __builtin_amdgcn_s_setprio(1);
#pragma unroll
    for (int hh = 0; hh < 2; ++hh)
#pragma unroll
      for (int m = 0; m < 4; ++m)
#pragma unroll
        for (int n = 0; n < 3; ++n)
          acc[m + 4][n] = __builtin_amdgcn_mfma_f32_16x16x32_bf16(af2[m][hh], bfv[n][hh], acc[m + 4][n], 0, 0, 0);
    __builtin_amdgcn_s_setprio(0);

    if (kt + 2 < NT) {
      asm volatile("s_waitcnt vmcnt(8)" ::: "memory");
    } else if (kt + 1 < NT) {
      asm volatile("s_waitcnt vmcnt(0)" ::: "memory");
    }
    if (kt + 1 < NT) __builtin_amdgcn_s_barrier();
  }

  // epilogue: RoPE + layout
#pragma unroll
  for (int m = 0; m < 8; ++m) {
    int row_l = m * 16 + (g << 2);
#pragma unroll
    for (int n = 0; n < 3; ++n) {
      int col = n0 + wc * 48 + n * 16 + l15;
#pragma unroll
      for (int r = 0; r < 4; ++r) {
        int row = m0 + row_l + r;
        float v = acc[m][n][r];
        int b = row >> 10, t = row & 1023;
        int sec = col >> 11;
        int c2 = col & 2047;
        int h = c2 >> 5, d = c2 & 31;
        float partner = __shfl_xor(v, 1);
        if (sec < 2) {
          float rot = (d & 1) ? partner : -partner;
          float cs = cosT[t * 32 + d], sn = sinT[t * 32 + d];
          float o = v * cs + rot * sn;
          if (sec == 0) o *= 0.17677669529663687f;
          __bf16* dst = sec ? Ko : Qo;
          dst[((size_t)((b << 6) | h) * Tlen + t) * HD + d] = (__bf16)o;
        } else {
          Vto[((size_t)((b << 6) | h) * HD + d) * Tlen + t] = (__bf16)v;
        }
      }
    }
  }
}

// ---------- 2-phase GEMM (projection). vmcnt parameterized by issue count ----------
// For <128,64,2,2>: nA=4, nB=2 -> 6 issues/tile; vmcnt must be 6 (vmcnt(8)
// would leave 2 of tile kt's loads pending at the barrier -> race).
template <int BM, int BN, int WM, int WN>
__launch_bounds__(WM * WN * 64)
__global__ void k_gemm(const __bf16* __restrict__ A, const __bf16* __restrict__ Bt,
                       int M, int N, int K, float* __restrict__ Cout) {
  constexpr int T = WM * WN * 64;
  constexpr int M_rep = BM / (WM * 16);
  constexpr int N_rep = BN / (WN * 16);
  constexpr int nA = (BM * 128) / (T * 16);
  constexpr int nB = (BN * 128) / (T * 16);
  constexpr int NISSUE = nA + nB;
  constexpr int ROWS_PER_ISSUE = T / 8;

  __shared__ alignas(16) __bf16 As[2][BM * 64];
  __shared__ alignas(16) __bf16 Bs[2][BN * 64];

  const int tid = threadIdx.x;
  const int lane = tid & 63;
  const int wave = tid >> 6;
  const int wr = wave / WN, wc = wave % WN;
  const int l15 = lane & 15;

  const int nwg = gridDim.x * gridDim.y;
  const int bid = blockIdx.y * gridDim.x + blockIdx.x;
  const int cpx = nwg >> 3;
  const int tswz = (bid & 7) * cpx + (bid >> 3);
  const int bx = tswz % gridDim.x, by = tswz / gridDim.x;
  const int m0 = by * BM, n0 = bx * BN;

  f32x4 acc[M_rep][N_rep] = {};

  const int srcChunkElem = ((lane & 7) ^ (lane >> 3)) * 8;
  const int rowInWave = wave * 8 + (lane >> 3);

  const int NT = K >> 6;

  auto stage = [&](int buf, int kt) {
    const int k0 = kt << 6;
#pragma unroll
    for (int i = 0; i < nA; ++i) {
      int row = i * ROWS_PER_ISSUE + rowInWave;
      gload_lds16(A + (size_t)(m0 + row) * K + k0 + srcChunkElem,
                  &As[buf][(i * T + wave * 64) * 8]);
    }
#pragma unroll
    for (int i = 0; i < nB; ++i) {
      int row = i * ROWS_PER_ISSUE + rowInWave;
      gload_lds16(Bt + (size_t)(n0 + row) * K + k0 + srcChunkElem,
                  &Bs[buf][(i * T + wave * 64) * 8]);
    }
  };

  stage(0, 0);

  for (int kt = 0; kt < NT; ++kt) {
    const int cur = kt & 1;
    if (kt + 1 < NT) {
      stage(cur ^ 1, kt + 1);
      if constexpr (NISSUE == 8)
        asm volatile("s_waitcnt vmcnt(8)" ::: "memory");
      else if constexpr (NISSUE == 6)
        asm volatile("s_waitcnt vmcnt(6)" ::: "memory");
      else
        asm volatile("s_waitcnt vmcnt(0)" ::: "memory");
    } else {
      asm volatile("s_waitcnt vmcnt(0)" ::: "memory");
    }
    __builtin_amdgcn_s_barrier();

    const char* ab = (const char*)&As[cur][0];
    const char* bb = (const char*)&Bs[cur][0];
#pragma unroll
    for (int hh = 0; hh < 2; ++hh) {
      bf16x8 af[M_rep], bfv[N_rep];
#pragma unroll
      for (int m = 0; m < M_rep; ++m) {
        int ar = wr * (M_rep * 16) + m * 16 + l15;
        int chunk = ((4 * hh + (lane >> 4)) ^ (lane & 7));
        af[m] = *(const bf16x8*)(ab + ar * 128 + chunk * 16);
      }
#pragma unroll
      for (int n = 0; n < N_rep; ++n) {
        int br = wc * (N_rep * 16) + n * 16 + l15;
        int chunk = ((4 * hh + (lane >> 4)) ^ (lane & 7));
        bfv[n] = *(const bf16x8*)(bb + br * 128 + chunk * 16);
      }
      __builtin_amdgcn_s_setprio(1);
#pragma unroll
      for (int m = 0; m < M_rep; ++m)
#pragma unroll
        for (int n = 0; n < N_rep; ++n)
          acc[m][n] = __builtin_amdgcn_mfma_f32_16x16x32_bf16(af[m], bfv[n], acc[m][n], 0, 0, 0);
      __builtin_amdgcn_s_setprio(0);
    }
    __builtin_amdgcn_s_barrier();
  }

#pragma unroll
  for (int m = 0; m < M_rep; ++m) {
    int row_l = wr * (M_rep * 16) + m * 16 + ((lane >> 4) << 2);
#pragma unroll
    for (int n = 0; n < N_rep; ++n) {
      int col = n0 + wc * (N_rep * 16) + n * 16 + l15;
#pragma unroll
      for (int r = 0; r < 4; ++r) {
        int row = m0 + row_l + r;
        Cout[(size_t)row * N + col] = acc[m][n][r];
      }
    }
  }
}

// ---------- flash attention: swapped QK^T, KVBLK=64, static softmax ----------
// R13 change: K-fragment register prefetch (kf for kt+1 loaded during kt's
// softmax/PV; zero load->use distance eliminated). vf already has the
// softmax between its load and PV use.
__launch_bounds__(256)
__global__ void k_attn(const __bf16* __restrict__ Q, const __bf16* __restrict__ Kmat,
                       const __bf16* __restrict__ Vt, __bf16* __restrict__ att) {
  __shared__ alignas(16) __bf16 P[4][32 * 72];
  const int tid = threadIdx.x;
  const int lane = tid & 63;
  const int w = tid >> 6;

  const int orig = blockIdx.y * gridDim.x + blockIdx.x;  // [0,1024)
  const int idx = orig >> 3;                             // [0,128)
  const int bh = (orig & 7) * 16 + (idx >> 3);           // 16 heads per XCD
  const int j = idx & 7;                                 // [0,8)

  const int qt = (w == 0) ? 2 * j : (w == 1) ? 2 * j + 1 : (w == 2) ? 30 - 2 * j : 31 - 2 * j;
  const int q0 = qt * 32;

  const __bf16* Qb = Q + (size_t)bh * Tlen * HD;
  const __bf16* Kb = Kmat + (size_t)bh * Tlen * HD;
  const __bf16* Vb = Vt + (size_t)bh * HD * Tlen;
  __bf16* Pw = &P[w][0];

  const int l15 = lane & 15;
  const int g = lane >> 4;
  const int lk8 = g * 8;

  bf16x8 qf[2];
#pragma unroll
  for (int m = 0; m < 2; ++m)
    qf[m] = *(const bf16x8*)(Qb + (size_t)(q0 + m * 16 + l15) * HD + lk8);

  f32x4 o[2][2] = {};
  float lsum[2] = {0.f, 0.f};

  const int nfull = q0 >> 6;

  // prefetch kt=0's K fragments
  bf16x8 kfA[4];
#pragma unroll
  for (int n = 0; n < 4; ++n)
    kfA[n] = *(const bf16x8*)(Kb + (size_t)(n * 16 + l15) * HD + lk8);

  for (int kt = 0; kt <= nfull; ++kt) {
    const int k0 = kt * 64;

    // issue next tile's kf early (used next iteration)
    bf16x8 kfN[4] = {};
    if (kt < nfull) {
#pragma unroll
      for (int n = 0; n < 4; ++n)
        kfN[n] = *(const bf16x8*)(Kb + (size_t)(k0 + 64 + n * 16 + l15) * HD + lk8);
    }

    f32x4 st[4][2] = {};
#pragma unroll
    for (int n = 0; n < 4; ++n)
#pragma unroll
      for (int m = 0; m < 2; ++m)
        st[n][m] = __builtin_amdgcn_mfma_f32_16x16x32_bf16(kfA[n], qf[m], st[n][m], 0, 0, 0);

    bf16x8 vf[2][2];
#pragma unroll
    for (int nn = 0; nn < 2; ++nn)
#pragma unroll
      for (int c = 0; c < 2; ++c)
        vf[nn][c] = *(const bf16x8*)(Vb + (size_t)(nn * 16 + l15) * Tlen + k0 + c * 32 + lk8);

    if (kt == nfull) {
#pragma unroll
      for (int n = 0; n < 4; ++n)
#pragma unroll
        for (int m = 0; m < 2; ++m)
#pragma unroll
          for (int r = 0; r < 4; ++r) {
            int kk = k0 + n * 16 + 4 * g + r;
            int qq = q0 + m * 16 + l15;
            if (kk > qq) st[n][m][r] = -1e30f;
          }
    }

#pragma unroll
    for (int m = 0; m < 2; ++m) {
      float p[16];
      float ps = 0.f;
#pragma unroll
      for (int n = 0; n < 4; ++n)
#pragma unroll
        for (int r = 0; r < 4; ++r) {
          float pv = __expf(st[n][m][r]);
          p[n * 4 + r] = pv;
          ps += pv;
        }
      ps += __shfl_xor(ps, 16);
      ps += __shfl_xor(ps, 32);
      lsum[m] += ps;

#pragma unroll
      for (int n = 0; n < 4; ++n) {
        unsigned int u0 = ((unsigned int)bfbits(p[n * 4 + 1]) << 16) | bfbits(p[n * 4 + 0]);
        unsigned int u1 = ((unsigned int)bfbits(p[n * 4 + 3]) << 16) | bfbits(p[n * 4 + 2]);
        int base = (m * 16 + l15) * 72 + n * 16 + 4 * g;
        *(unsigned int*)&Pw[base] = u0;
        *(unsigned int*)&Pw[base + 2] = u1;
      }
    }

    bf16x8 pa[2][2];
#pragma unroll
    for (int m = 0; m < 2; ++m)
#pragma unroll
      for (int c = 0; c < 2; ++c)
        pa[m][c] = *(const bf16x8*)&Pw[(m * 16 + l15) * 72 + c * 32 + lk8];

#pragma unroll
    for (int m = 0; m < 2; ++m)
#pragma unroll
      for (int nn = 0; nn < 2; ++nn)
#pragma unroll
        for (int c = 0; c < 2; ++c)
          o[m][nn] = __builtin_amdgcn_mfma_f32_16x16x32_bf16(pa[m][c], vf[nn][c], o[m][nn], 0, 0, 0);

    if (kt < nfull) {
#pragma unroll
      for (int n = 0; n < 4; ++n) kfA[n] = kfN[n];
    }
  }

  const int b = bh >> 6;
  const int h = bh & 63;
#pragma unroll
  for (int m = 0; m < 2; ++m) {
#pragma unroll
    for (int r = 0; r < 4; ++r) {
      float ls = __shfl(lsum[m], (lane & 48) + ((lane >> 4) << 2) + r);
      float inv = 1.0f / ls;
      int t = q0 + m * 16 + 4 * g + r;
#pragma unroll
      for (int nn = 0; nn < 2; ++nn) {
        float ov = o[m][nn][r] * inv;
        att[((size_t)(b * Tlen + t)) * 2048 + h * 32 + nn * 16 + l15] = (__bf16)ov;
      }
    }
  }
}

// ---------- launch ----------

extern "C" void kernel_launch(void* const* d_in, const int* in_sizes, int n_in,
                              void* d_out, int out_size, void* d_ws, size_t ws_size,
                              hipStream_t stream) {
  const float* x = (const float*)d_in[0];
  const float* pos = (const float*)d_in[1];
  const float* w_attn = (const float*)d_in[2];
  const float* w_proj = (const float*)d_in[3];
  float* out = (float*)d_out;

  char* ws = (char*)d_ws;
  size_t off = 0;
  auto alloc = [&](size_t bytes) {
    void* p = ws + off;
    off = (off + bytes + 255) & ~(size_t)255;
    return p;
  };
  __bf16* xb  = (__bf16*)alloc(2048ull * 2048 * 2);
  __bf16* waT = (__bf16*)alloc(6144ull * 2048 * 2);
  __bf16* wpT = (__bf16*)alloc(2048ull * 2048 * 2);
  __bf16* Qb  = (__bf16*)alloc(2ull * 64 * 1024 * 32 * 2);
  __bf16* Kb  = (__bf16*)alloc(2ull * 64 * 1024 * 32 * 2);
  __bf16* Vtb = (__bf16*)alloc(2ull * 64 * 32 * 1024 * 2);
  __bf16* att = (__bf16*)alloc(2048ull * 2048 * 2);
  float* cosT = (float*)alloc(1024ull * 32 * 4);
  float* sinT = (float*)alloc(1024ull * 32 * 4);

  // fused staging
  k_stage<<<6272, 256, 0, stream>>>(x, xb, w_attn, waT, w_proj, wpT, pos, cosT, sinT);

  // qkv = xb @ waT^T with fused RoPE + layout (128x192, 512 blocks = 2/CU)
  k_gemmqkv<<<512, 256, 0, stream>>>(
      xb, waT, 2048, 6144, 2048, Qb, Kb, Vtb, cosT, sinT);

  k_attn<<<dim3(8, 128), 256, 0, stream>>>(Qb, Kb, Vtb, att);

  // out = att @ wpT^T (128x64 tile, 512 blocks = 2/CU)
  k_gemm<128, 64, 2, 2><<<dim3(2048 / 64, 2048 / 128), 256, 0, stream>>>(
      att, wpT, 2048, 2048, 2048, out);
}

// Round 14
// 150.014 us; speedup vs baseline: 1.2722x; 1.0470x over previous
//
#include <hip/hip_runtime.h>
#include <hip/hip_bf16.h>
#include <math.h>

typedef __attribute__((ext_vector_type(8))) __bf16 bf16x8;
typedef __attribute__((ext_vector_type(4))) __bf16 bf16x4;
typedef __attribute__((ext_vector_type(4))) float f32x4;

#define DEVINL static __device__ __forceinline__

static constexpr int Tlen = 1024;
static constexpr int HD = 32;

DEVINL void gload_lds16(const void* g, void* l) {
  __builtin_amdgcn_global_load_lds(
      (const __attribute__((address_space(1))) void*)g,
      (__attribute__((address_space(3))) void*)l, 16, 0, 0);
}

DEVINL unsigned short bfbits(float x) {
  __bf16 b = (__bf16)x;
  return __builtin_bit_cast(unsigned short, b);
}

// ---------- fused staging kernel: cvt | transpose(w_attn) | transpose(w_proj) | sincos ----
__global__ void k_stage(const float* __restrict__ x, __bf16* __restrict__ xb,
                        const float* __restrict__ w_attn, __bf16* __restrict__ waT,
                        const float* __restrict__ w_proj, __bf16* __restrict__ wpT,
                        const float* __restrict__ pos, float* __restrict__ cosT,
                        float* __restrict__ sinT) {
  const int bid = blockIdx.x;
  if (bid < 2048) {
    int i = (bid * 256 + threadIdx.x) * 8;
    const float4* p = (const float4*)(x + i);
    float4 a = p[0], b = p[1];
    bf16x8 v;
    v[0] = (__bf16)a.x; v[1] = (__bf16)a.y; v[2] = (__bf16)a.z; v[3] = (__bf16)a.w;
    v[4] = (__bf16)b.x; v[5] = (__bf16)b.y; v[6] = (__bf16)b.z; v[7] = (__bf16)b.w;
    *(bf16x8*)(xb + i) = v;
    return;
  }
  if (bid >= 6144) {
    int idx = (bid - 6144) * 256 + threadIdx.x;  // T*32
    int t = idx >> 5, d = idx & 31;
    float invf = powf(10000.0f, -(float)d * (1.0f / 32.0f));
    float ang = pos[t] * invf;
    cosT[idx] = cosf(ang);
    sinT[idx] = sinf(ang);
    return;
  }
  const float* w;
  __bf16* wt;
  int n0, k0, K, N;
  if (bid < 5120) {  // w_attn: 3072 blocks
    int t = bid - 2048;
    w = w_attn; wt = waT; K = 2048; N = 6144;
    n0 = (t % 96) * 64; k0 = (t / 96) * 64;
  } else {           // w_proj: 1024 blocks
    int t = bid - 5120;
    w = w_proj; wt = wpT; K = 2048; N = 2048;
    n0 = (t % 32) * 64; k0 = (t / 32) * 64;
  }
  __shared__ float tile[64][65];
  const int tx = threadIdx.x & 15;
  const int ty = threadIdx.x >> 4;
#pragma unroll
  for (int i = 0; i < 4; ++i) {
    float4 v = *(const float4*)&w[(size_t)(k0 + ty + i * 16) * N + n0 + tx * 4];
    tile[ty + i * 16][tx * 4 + 0] = v.x;
    tile[ty + i * 16][tx * 4 + 1] = v.y;
    tile[ty + i * 16][tx * 4 + 2] = v.z;
    tile[ty + i * 16][tx * 4 + 3] = v.w;
  }
  __syncthreads();
#pragma unroll
  for (int i = 0; i < 4; ++i) {
    int n = ty + i * 16;
    bf16x4 s;
#pragma unroll
    for (int j = 0; j < 4; ++j) s[j] = (__bf16)tile[tx * 4 + j][n];
    *(bf16x4*)&wt[(size_t)(n0 + n) * K + k0 + tx * 4] = s;
  }
}

// ---------- 2-phase dbuf GEMM template, 512 threads = 8 waves (WM x WN) ----------
// R14 experiment: 4 waves/SIMD (16 waves/CU at 2 blocks/CU) vs the 2/SIMD all
// prior rounds ran. Same tiles, same counted-vmcnt 2-phase schedule.
// vmcnt = NISSUE (leave next tile's issues in flight, drain current tile).
// MODE 0: fp32 store (XCD tswz mapping, 2D grid).
// MODE 1: RoPE epilogue (by-clustered mapping, 1D grid of 512).
template <int BM, int BN, int WM, int WN, int MODE>
__launch_bounds__(WM * WN * 64, 4)
__global__ void k_gemm(const __bf16* __restrict__ A, const __bf16* __restrict__ Bt,
                       int M, int N, int K, float* __restrict__ Cout,
                       __bf16* __restrict__ Qo, __bf16* __restrict__ Ko,
                       __bf16* __restrict__ Vto, const float* __restrict__ cosT,
                       const float* __restrict__ sinT) {
  constexpr int T = WM * WN * 64;
  constexpr int M_rep = BM / (WM * 16);
  constexpr int N_rep = BN / (WN * 16);
  constexpr int nA = (BM * 128) / (T * 16);
  constexpr int nB = (BN * 128) / (T * 16);
  constexpr int NISSUE = nA + nB;
  constexpr int ROWS_PER_ISSUE = T / 8;

  __shared__ alignas(16) __bf16 As[2][BM * 64];
  __shared__ alignas(16) __bf16 Bs[2][BN * 64];

  const int tid = threadIdx.x;
  const int lane = tid & 63;
  const int wave = tid >> 6;
  const int wr = wave / WN, wc = wave % WN;
  const int l15 = lane & 15;
  const int g = lane >> 4;

  int bx, by;
  if (MODE == 1) {
    // by-clustered: XCD x owns by in {2x, 2x+1} -> 1 MB A-panel L2-resident
    const int bid = blockIdx.x;         // [0,512)
    const int u = bid >> 3;             // [0,64)
    by = 2 * (bid & 7) + (u & 1);       // [0,16)
    bx = u >> 1;                        // [0,32)
  } else {
    const int nwg = gridDim.x * gridDim.y;
    const int bid = blockIdx.y * gridDim.x + blockIdx.x;
    const int cpx = nwg >> 3;
    const int tswz = (bid & 7) * cpx + (bid >> 3);
    bx = tswz % gridDim.x;
    by = tswz / gridDim.x;
  }
  const int m0 = by * BM, n0 = bx * BN;

  f32x4 acc[M_rep][N_rep] = {};

  const int srcChunkElem = ((lane & 7) ^ (lane >> 3)) * 8;
  const int rowInWave = wave * 8 + (lane >> 3);

  const int NT = K >> 6;

  auto stage = [&](int buf, int kt) {
    const int k0 = kt << 6;
#pragma unroll
    for (int i = 0; i < nA; ++i) {
      int row = i * ROWS_PER_ISSUE + rowInWave;
      gload_lds16(A + (size_t)(m0 + row) * K + k0 + srcChunkElem,
                  &As[buf][(i * T + wave * 64) * 8]);
    }
#pragma unroll
    for (int i = 0; i < nB; ++i) {
      int row = i * ROWS_PER_ISSUE + rowInWave;
      gload_lds16(Bt + (size_t)(n0 + row) * K + k0 + srcChunkElem,
                  &Bs[buf][(i * T + wave * 64) * 8]);
    }
  };

  stage(0, 0);

  for (int kt = 0; kt < NT; ++kt) {
    const int cur = kt & 1;
    if (kt + 1 < NT) {
      stage(cur ^ 1, kt + 1);
      if constexpr (NISSUE == 8)
        asm volatile("s_waitcnt vmcnt(8)" ::: "memory");
      else if constexpr (NISSUE == 6)
        asm volatile("s_waitcnt vmcnt(6)" ::: "memory");
      else if constexpr (NISSUE == 5)
        asm volatile("s_waitcnt vmcnt(5)" ::: "memory");
      else if constexpr (NISSUE == 3)
        asm volatile("s_waitcnt vmcnt(3)" ::: "memory");
      else
        asm volatile("s_waitcnt vmcnt(0)" ::: "memory");
    } else {
      asm volatile("s_waitcnt vmcnt(0)" ::: "memory");
    }
    __builtin_amdgcn_s_barrier();

    const char* ab = (const char*)&As[cur][0];
    const char* bb = (const char*)&Bs[cur][0];
#pragma unroll
    for (int hh = 0; hh < 2; ++hh) {
      bf16x8 af[M_rep], bfv[N_rep];
#pragma unroll
      for (int m = 0; m < M_rep; ++m) {
        int ar = wr * (M_rep * 16) + m * 16 + l15;
        int chunk = ((4 * hh + g) ^ (lane & 7));
        af[m] = *(const bf16x8*)(ab + ar * 128 + chunk * 16);
      }
#pragma unroll
      for (int n = 0; n < N_rep; ++n) {
        int br = wc * (N_rep * 16) + n * 16 + l15;
        int chunk = ((4 * hh + g) ^ (lane & 7));
        bfv[n] = *(const bf16x8*)(bb + br * 128 + chunk * 16);
      }
      __builtin_amdgcn_s_setprio(1);
#pragma unroll
      for (int m = 0; m < M_rep; ++m)
#pragma unroll
        for (int n = 0; n < N_rep; ++n)
          acc[m][n] = __builtin_amdgcn_mfma_f32_16x16x32_bf16(af[m], bfv[n], acc[m][n], 0, 0, 0);
      __builtin_amdgcn_s_setprio(0);
    }
    __builtin_amdgcn_s_barrier();
  }

  // epilogue
#pragma unroll
  for (int m = 0; m < M_rep; ++m) {
    int row_l = wr * (M_rep * 16) + m * 16 + (g << 2);
#pragma unroll
    for (int n = 0; n < N_rep; ++n) {
      int col = n0 + wc * (N_rep * 16) + n * 16 + l15;
#pragma unroll
      for (int r = 0; r < 4; ++r) {
        int row = m0 + row_l + r;
        float v = acc[m][n][r];
        if (MODE == 0) {
          Cout[(size_t)row * N + col] = v;
        } else {
          int b = row >> 10, t = row & 1023;
          int sec = col >> 11;           // 0=q,1=k,2=v (per-lane)
          int c2 = col & 2047;
          int h = c2 >> 5, d = c2 & 31;
          float partner = __shfl_xor(v, 1);  // unconditional, before divergence
          if (sec < 2) {
            float rot = (d & 1) ? partner : -partner;
            float cs = cosT[t * 32 + d], sn = sinT[t * 32 + d];
            float o = v * cs + rot * sn;
            if (sec == 0) o *= 0.17677669529663687f;  // fold 1/sqrt(hd) into Q
            __bf16* dst = sec ? Ko : Qo;
            dst[((size_t)((b << 6) | h) * Tlen + t) * HD + d] = (__bf16)o;
          } else {
            Vto[((size_t)((b << 6) | h) * HD + d) * Tlen + t] = (__bf16)v;
          }
        }
      }
    }
  }
}

// ---------- flash attention: swapped QK^T, KVBLK=64, static softmax, kf prefetch ----
__launch_bounds__(256)
__global__ void k_attn(const __bf16* __restrict__ Q, const __bf16* __restrict__ Kmat,
                       const __bf16* __restrict__ Vt, __bf16* __restrict__ att) {
  __shared__ alignas(16) __bf16 P[4][32 * 72];
  const int tid = threadIdx.x;
  const int lane = tid & 63;
  const int w = tid >> 6;

  const int orig = blockIdx.y * gridDim.x + blockIdx.x;  // [0,1024)
  const int idx = orig >> 3;                             // [0,128)
  const int bh = (orig & 7) * 16 + (idx >> 3);           // 16 heads per XCD
  const int j = idx & 7;                                 // [0,8)

  const int qt = (w == 0) ? 2 * j : (w == 1) ? 2 * j + 1 : (w == 2) ? 30 - 2 * j : 31 - 2 * j;
  const int q0 = qt * 32;

  const __bf16* Qb = Q + (size_t)bh * Tlen * HD;
  const __bf16* Kb = Kmat + (size_t)bh * Tlen * HD;
  const __bf16* Vb = Vt + (size_t)bh * HD * Tlen;
  __bf16* Pw = &P[w][0];

  const int l15 = lane & 15;
  const int g = lane >> 4;
  const int lk8 = g * 8;

  bf16x8 qf[2];
#pragma unroll
  for (int m = 0; m < 2; ++m)
    qf[m] = *(const bf16x8*)(Qb + (size_t)(q0 + m * 16 + l15) * HD + lk8);

  f32x4 o[2][2] = {};
  float lsum[2] = {0.f, 0.f};

  const int nfull = q0 >> 6;

  bf16x8 kfA[4];
#pragma unroll
  for (int n = 0; n < 4; ++n)
    kfA[n] = *(const bf16x8*)(Kb + (size_t)(n * 16 + l15) * HD + lk8);

  for (int kt = 0; kt <= nfull; ++kt) {
    const int k0 = kt * 64;

    bf16x8 kfN[4] = {};
    if (kt < nfull) {
#pragma unroll
      for (int n = 0; n < 4; ++n)
        kfN[n] = *(const bf16x8*)(Kb + (size_t)(k0 + 64 + n * 16 + l15) * HD + lk8);
    }

    f32x4 st[4][2] = {};
#pragma unroll
    for (int n = 0; n < 4; ++n)
#pragma unroll
      for (int m = 0; m < 2; ++m)
        st[n][m] = __builtin_amdgcn_mfma_f32_16x16x32_bf16(kfA[n], qf[m], st[n][m], 0, 0, 0);

    bf16x8 vf[2][2];
#pragma unroll
    for (int nn = 0; nn < 2; ++nn)
#pragma unroll
      for (int c = 0; c < 2; ++c)
        vf[nn][c] = *(const bf16x8*)(Vb + (size_t)(nn * 16 + l15) * Tlen + k0 + c * 32 + lk8);

    if (kt == nfull) {
#pragma unroll
      for (int n = 0; n < 4; ++n)
#pragma unroll
        for (int m = 0; m < 2; ++m)
#pragma unroll
          for (int r = 0; r < 4; ++r) {
            int kk = k0 + n * 16 + 4 * g + r;
            int qq = q0 + m * 16 + l15;
            if (kk > qq) st[n][m][r] = -1e30f;
          }
    }

#pragma unroll
    for (int m = 0; m < 2; ++m) {
      float p[16];
      float ps = 0.f;
#pragma unroll
      for (int n = 0; n < 4; ++n)
#pragma unroll
        for (int r = 0; r < 4; ++r) {
          float pv = __expf(st[n][m][r]);
          p[n * 4 + r] = pv;
          ps += pv;
        }
      ps += __shfl_xor(ps, 16);
      ps += __shfl_xor(ps, 32);
      lsum[m] += ps;

#pragma unroll
      for (int n = 0; n < 4; ++n) {
        unsigned int u0 = ((unsigned int)bfbits(p[n * 4 + 1]) << 16) | bfbits(p[n * 4 + 0]);
        unsigned int u1 = ((unsigned int)bfbits(p[n * 4 + 3]) << 16) | bfbits(p[n * 4 + 2]);
        int base = (m * 16 + l15) * 72 + n * 16 + 4 * g;
        *(unsigned int*)&Pw[base] = u0;
        *(unsigned int*)&Pw[base + 2] = u1;
      }
    }

    bf16x8 pa[2][2];
#pragma unroll
    for (int m = 0; m < 2; ++m)
#pragma unroll
      for (int c = 0; c < 2; ++c)
        pa[m][c] = *(const bf16x8*)&Pw[(m * 16 + l15) * 72 + c * 32 + lk8];

#pragma unroll
    for (int m = 0; m < 2; ++m)
#pragma unroll
      for (int nn = 0; nn < 2; ++nn)
#pragma unroll
        for (int c = 0; c < 2; ++c)
          o[m][nn] = __builtin_amdgcn_mfma_f32_16x16x32_bf16(pa[m][c], vf[nn][c], o[m][nn], 0, 0, 0);

    if (kt < nfull) {
#pragma unroll
      for (int n = 0; n < 4; ++n) kfA[n] = kfN[n];
    }
  }

  const int b = bh >> 6;
  const int h = bh & 63;
#pragma unroll
  for (int m = 0; m < 2; ++m) {
#pragma unroll
    for (int r = 0; r < 4; ++r) {
      float ls = __shfl(lsum[m], (lane & 48) + ((lane >> 4) << 2) + r);
      float inv = 1.0f / ls;
      int t = q0 + m * 16 + 4 * g + r;
#pragma unroll
      for (int nn = 0; nn < 2; ++nn) {
        float ov = o[m][nn][r] * inv;
        att[((size_t)(b * Tlen + t)) * 2048 + h * 32 + nn * 16 + l15] = (__bf16)ov;
      }
    }
  }
}

// ---------- launch ----------

extern "C" void kernel_launch(void* const* d_in, const int* in_sizes, int n_in,
                              void* d_out, int out_size, void* d_ws, size_t ws_size,
                              hipStream_t stream) {
  const float* x = (const float*)d_in[0];
  const float* pos = (const float*)d_in[1];
  const float* w_attn = (const float*)d_in[2];
  const float* w_proj = (const float*)d_in[3];
  float* out = (float*)d_out;

  char* ws = (char*)d_ws;
  size_t off = 0;
  auto alloc = [&](size_t bytes) {
    void* p = ws + off;
    off = (off + bytes + 255) & ~(size_t)255;
    return p;
  };
  __bf16* xb  = (__bf16*)alloc(2048ull * 2048 * 2);
  __bf16* waT = (__bf16*)alloc(6144ull * 2048 * 2);
  __bf16* wpT = (__bf16*)alloc(2048ull * 2048 * 2);
  __bf16* Qb  = (__bf16*)alloc(2ull * 64 * 1024 * 32 * 2);
  __bf16* Kb  = (__bf16*)alloc(2ull * 64 * 1024 * 32 * 2);
  __bf16* Vtb = (__bf16*)alloc(2ull * 64 * 32 * 1024 * 2);
  __bf16* att = (__bf16*)alloc(2048ull * 2048 * 2);
  float* cosT = (float*)alloc(1024ull * 32 * 4);
  float* sinT = (float*)alloc(1024ull * 32 * 4);

  // fused staging
  k_stage<<<6272, 256, 0, stream>>>(x, xb, w_attn, waT, w_proj, wpT, pos, cosT, sinT);

  // qkv = xb @ waT^T (128x192 tile, 8 waves of 2x4, 512 blocks = 2/CU -> 4 waves/SIMD)
  k_gemm<128, 192, 2, 4, 1><<<512, 512, 0, stream>>>(
      xb, waT, 2048, 6144, 2048, nullptr, Qb, Kb, Vtb, cosT, sinT);

  k_attn<<<dim3(8, 128), 256, 0, stream>>>(Qb, Kb, Vtb, att);

  // out = att @ wpT^T (128x64 tile, 8 waves of 2x4, 512 blocks)
  k_gemm<128, 64, 2, 4, 0><<<dim3(32, 16), 512, 0, stream>>>(
      att, wpT, 2048, 2048, 2048, out, nullptr, nullptr, nullptr, nullptr, nullptr);
}